// Round 7
// baseline (1326.397 us; speedup 1.0000x reference)
//
#include <hip/hip_runtime.h>
#include <hip/hip_cooperative_groups.h>
#include <math.h>

// MultiTaskGNN: 2-layer GAT + BN + ELU + two heads. N=50000, E=400000.
// R7: cooperative build at FULL occupancy (2048 blocks, fallback chain),
// edge weights computed inline in agg phase-A (wave-local LDS, no ew pass),
// 8/16-edges-in-flight gather loops. 5 dispatches total.

namespace cg = cooperative_groups;

typedef unsigned short ushort_t;
typedef __attribute__((ext_vector_type(8))) unsigned short ushort8;
typedef __attribute__((ext_vector_type(4))) unsigned short ushort4v;
typedef __attribute__((ext_vector_type(8))) short short8;
typedef __attribute__((ext_vector_type(4))) float f32x4;

#define EPS_BN 1e-5f

__device__ __forceinline__ ushort_t f2bf(float f) {  // RNE
  unsigned u = __float_as_uint(f);
  unsigned r = u + 0x7fffu + ((u >> 16) & 1u);
  return (ushort_t)(r >> 16);
}
__device__ __forceinline__ float bf2f(ushort_t h) {
  return __uint_as_float((unsigned)h << 16);
}
__device__ __forceinline__ float leaky02(float x) { return x >= 0.f ? x : 0.2f * x; }
__device__ __forceinline__ float elu_fast(float x) {
  return x > 0.f ? x : __expf(x) - 1.f;
}
__device__ __forceinline__ float wave_sum(float v) {
#pragma unroll
  for (int o = 1; o < 64; o <<= 1) v += __shfl_xor(v, o, 64);
  return v;
}
__device__ __forceinline__ int wave_incl_scan(int v, int lane) {
#pragma unroll
  for (int off = 1; off < 64; off <<= 1) {
    int t = __shfl_up(v, off, 64);
    if (lane >= off) v += t;
  }
  return v;
}

__device__ __forceinline__ void gld_lds16(const ushort_t* g, ushort_t* l) {
  __builtin_amdgcn_global_load_lds(
      (const __attribute__((address_space(1))) unsigned int*)g,
      (__attribute__((address_space(3))) unsigned int*)l, 16, 0, 0);
}

// ---------------- cooperative graph build (grid-size generic) ----------------
struct BuildArgs {
  const int* src; const int* dst; int E; int N; int CH;
  int* counts; int* cursor; int* offsets; int* partials; int* pprefix;
  int* csr_src;
  const float* W1; const float* W2; ushort_t* W1t; ushort_t* W2t;
  const float* b1; const float* bn1w; const float* bn1b; const float* bn1m; const float* bn1v;
  const float* b2; const float* bn2w; const float* bn2b; const float* bn2m; const float* bn2v;
  float* S1; float* T1; float* S2; float* T2;
};

__global__ __launch_bounds__(256) void build_kernel(BuildArgs a) {
  cg::grid_group grid = cg::this_grid();
  const int tid = threadIdx.x;
  const int bid = blockIdx.x;
  const int gsz = gridDim.x * 256;
  const int gtid = bid * 256 + tid;
  __shared__ int lds[256];

  // P0: zero counters; transpose-cast weights; fold BN; zero csr pad
  for (int i = gtid; i < a.N; i += gsz) { a.counts[i] = 0; a.cursor[i] = 0; }
  for (int i = gtid; i < 256 * 256; i += gsz) {
    int k = i >> 8, n2 = i & 255;
    a.W1t[n2 * 256 + k] = f2bf(a.W1[i]);
  }
  for (int i = gtid; i < 256 * 64; i += gsz) {
    int k = i >> 6, n2 = i & 63;
    a.W2t[n2 * 256 + k] = f2bf(a.W2[i]);
  }
  if (gtid < 256) {
    float s = a.bn1w[gtid] * rsqrtf(a.bn1v[gtid] + EPS_BN);
    a.S1[gtid] = s;
    a.T1[gtid] = (a.b1[gtid] - a.bn1m[gtid]) * s + a.bn1b[gtid];
  } else if (gtid < 320) {
    int j = gtid - 256;
    float s = a.bn2w[j] * rsqrtf(a.bn2v[j] + EPS_BN);
    a.S2[j] = s;
    a.T2[j] = (a.b2[j] - a.bn2m[j]) * s + a.bn2b[j];
  } else if (gtid < 384) {
    a.csr_src[a.E + gtid - 320] = 0;
  }
  grid.sync();

  // P1: histogram of dst
  for (int e = gtid; e < a.E; e += gsz) atomicAdd(&a.counts[a.dst[e]], 1);
  grid.sync();

  // P2a: per-block chunk scan (CH elements, wave 0 only, 64-stripe with carry)
  if (tid < 64) {
    int carry = 0;
    for (int c = 0; c < a.CH; c += 64) {
      int idx = c + tid;
      int i = bid * a.CH + idx;
      int v = (idx < a.CH && i < a.N) ? a.counts[i] : 0;
      int incl = wave_incl_scan(v, tid);
      if (idx < a.CH && i < a.N) a.offsets[i] = carry + incl - v;
      carry += __shfl(incl, 63, 64);
    }
    if (tid == 63) a.partials[bid] = carry;
  }
  grid.sync();

  // P2b: block 0 scans gridDim.x partials (PP per thread)
  if (bid == 0) {
    const int PP = gridDim.x >> 8;  // 2048->8, 1024->4, 256->1
    int loc[8];
    int s = 0;
#pragma unroll 1
    for (int i = 0; i < PP; ++i) { loc[i] = a.partials[tid * PP + i]; s += loc[i]; }
    lds[tid] = s;
    __syncthreads();
    for (int o = 1; o < 256; o <<= 1) {
      int t = (tid >= o) ? lds[tid - o] : 0;
      __syncthreads();
      lds[tid] += t;
      __syncthreads();
    }
    int base = lds[tid] - s;  // exclusive
#pragma unroll 1
    for (int i = 0; i < PP; ++i) { a.pprefix[tid * PP + i] = base; base += loc[i]; }
    if (tid == 255) a.offsets[a.N] = lds[255];
  }
  grid.sync();

  // P2c: add chunk base (CH <= 256 for all supported grids)
  if (tid < a.CH) {
    int i = bid * a.CH + tid;
    if (i < a.N) a.offsets[i] += a.pprefix[bid];
  }
  grid.sync();

  // P3: scatter into CSR
  for (int e = gtid; e < a.E; e += gsz) {
    int d = a.dst[e];
    int p = atomicAdd(&a.cursor[d], 1);
    a.csr_src[a.offsets[d] + p] = a.src[e];
  }
}

// ---------------- MFMA bf16 GEMM + fused alpha epilogue ----------------
template <int WM, bool CASTA>
__global__ __launch_bounds__(WM * 64) void mfma_gemm_fused(
    const void* __restrict__ Ain, const ushort_t* __restrict__ Bt,
    ushort_t* __restrict__ C, const float* __restrict__ avs, const float* __restrict__ avd,
    float* __restrict__ as_out, float* __restrict__ ad_out, int M, int Nt, int K, int H) {
  constexpr int BM = WM * 32;
  constexpr int NB = 4 / WM;
  __shared__ ushort_t As[BM * 32];
  __shared__ ushort_t Bs[64 * 32];
  const int t = threadIdx.x;
  const int w = t >> 6, l = t & 63;
  const int m0 = blockIdx.y * BM;
  const int n0 = blockIdx.x * 64;
  const int head = n0 >> 6;

  f32x4 zero4 = {0.f, 0.f, 0.f, 0.f};
  f32x4 acc[2][4];
#pragma unroll
  for (int i = 0; i < 2; ++i)
#pragma unroll
    for (int j = 0; j < 4; ++j) acc[i][j] = zero4;

  const int scol = (l & 3) * 8;
  const ushort_t* Bgb[NB];
  ushort_t* Bsl[NB];
#pragma unroll
  for (int b = 0; b < NB; ++b) {
    int r = (b * WM + w) * 16 + (l >> 2);
    Bgb[b] = Bt + (size_t)(n0 + r) * K + scol;
    Bsl[b] = &Bs[(b * WM + w) * 512];
  }
  const ushort_t* Aga[2];
  ushort_t* Asl[2];
  const float* Axg = nullptr;
  ushort_t* AsWc = nullptr;
  if (CASTA) {
    int ar = t >> 1, ac = (t & 1) * 16;
    Axg = (const float*)Ain + (size_t)min(m0 + ar, M - 1) * K + ac;
    AsWc = &As[ar * 32 + ac];
  } else {
#pragma unroll
    for (int a = 0; a < 2; ++a) {
      int r = (a * WM + w) * 16 + (l >> 2);
      int gr = min(m0 + r, M - 1);
      Aga[a] = (const ushort_t*)Ain + (size_t)gr * K + scol;
      Asl[a] = &As[(a * WM + w) * 512];
    }
  }

  for (int k0 = 0; k0 < K; k0 += 32) {
    if (CASTA) {
      float4 f0 = *(const float4*)(Axg + k0);
      float4 f1 = *(const float4*)(Axg + k0 + 4);
      float4 f2 = *(const float4*)(Axg + k0 + 8);
      float4 f3 = *(const float4*)(Axg + k0 + 12);
      __syncthreads();
#pragma unroll
      for (int b = 0; b < NB; ++b) gld_lds16(Bgb[b] + k0, Bsl[b]);
      ushort8 u0, u1;
      u0[0] = f2bf(f0.x); u0[1] = f2bf(f0.y); u0[2] = f2bf(f0.z); u0[3] = f2bf(f0.w);
      u0[4] = f2bf(f1.x); u0[5] = f2bf(f1.y); u0[6] = f2bf(f1.z); u0[7] = f2bf(f1.w);
      u1[0] = f2bf(f2.x); u1[1] = f2bf(f2.y); u1[2] = f2bf(f2.z); u1[3] = f2bf(f2.w);
      u1[4] = f2bf(f3.x); u1[5] = f2bf(f3.y); u1[6] = f2bf(f3.z); u1[7] = f2bf(f3.w);
      *(ushort8*)AsWc = u0;
      *(ushort8*)(AsWc + 8) = u1;
      __syncthreads();
    } else {
      __syncthreads();
#pragma unroll
      for (int a = 0; a < 2; ++a) gld_lds16(Aga[a] + k0, Asl[a]);
#pragma unroll
      for (int b = 0; b < NB; ++b) gld_lds16(Bgb[b] + k0, Bsl[b]);
      __syncthreads();
    }
    const int kq = (l >> 4) * 8;
    short8 af[2], bfr[4];
#pragma unroll
    for (int i = 0; i < 2; ++i)
      af[i] = *(const short8*)&As[(w * 32 + i * 16 + (l & 15)) * 32 + kq];
#pragma unroll
    for (int j = 0; j < 4; ++j)
      bfr[j] = *(const short8*)&Bs[(j * 16 + (l & 15)) * 32 + kq];
#pragma unroll
    for (int i = 0; i < 2; ++i)
#pragma unroll
      for (int j = 0; j < 4; ++j)
        acc[i][j] = __builtin_amdgcn_mfma_f32_16x16x32_bf16(af[i], bfr[j], acc[i][j], 0, 0, 0);
  }

  const int rbase = m0 + w * 32 + (l >> 4) * 4;
  const int cbase = n0 + (l & 15);
#pragma unroll
  for (int i = 0; i < 2; ++i)
#pragma unroll
    for (int j = 0; j < 4; ++j)
#pragma unroll
      for (int r = 0; r < 4; ++r) {
        int row = rbase + i * 16 + r;
        if (row < M) C[(size_t)row * Nt + cbase + j * 16] = f2bf(acc[i][j][r]);
      }

  float asw[4], adw[4];
#pragma unroll
  for (int j = 0; j < 4; ++j) {
    asw[j] = avs[head * 64 + (l & 15) + j * 16];
    adw[j] = avd[head * 64 + (l & 15) + j * 16];
  }
#pragma unroll
  for (int i = 0; i < 2; ++i)
#pragma unroll
    for (int r = 0; r < 4; ++r) {
      float s_ = acc[i][0][r] * asw[0] + acc[i][1][r] * asw[1] +
                 acc[i][2][r] * asw[2] + acc[i][3][r] * asw[3];
      float d_ = acc[i][0][r] * adw[0] + acc[i][1][r] * adw[1] +
                 acc[i][2][r] * adw[2] + acc[i][3][r] * adw[3];
#pragma unroll
      for (int o = 1; o < 16; o <<= 1) {
        s_ += __shfl_xor(s_, o, 64);
        d_ += __shfl_xor(d_, o, 64);
      }
      if ((l & 15) == 0) {
        int row = rbase + i * 16 + r;
        if (row < M) {
          as_out[(size_t)row * H + head] = s_;
          ad_out[(size_t)row * H + head] = d_;
        }
      }
    }
}

// ---------------- layer 1 agg: inline weights via wave-local LDS ----------------
__global__ __launch_bounds__(256) void agg1_kernel(
    const ushort_t* __restrict__ h1, const int* __restrict__ offsets,
    const int* __restrict__ csr, const float* __restrict__ as1,
    const float* __restrict__ ad1,
    const float* __restrict__ S1, const float* __restrict__ T1,
    ushort_t* __restrict__ out, int N) {
  __shared__ float ldsW[4][64][4];
  __shared__ int ldsS[4][64];
  const int wv = threadIdx.x >> 6;
  int n = blockIdx.x * 4 + wv;
  int l = threadIdx.x & 63;
  if (n >= N) return;
  const int g = l >> 5, ll = l & 31, hh = ll >> 3;
  int off = offsets[n], deg = offsets[n + 1] - off;
  const int* csrp = csr + off;
  const size_t hoff = (size_t)ll * 8;
  float4 adn = *(const float4*)&ad1[n * 4];

  float acc[8] = {0, 0, 0, 0, 0, 0, 0, 0};
  float ds[4] = {0, 0, 0, 0};

  for (int base = 0; base < deg; base += 64) {
    int cnt = min(64, deg - base);
    // phase A (wave-local): weights for this chunk into LDS
    int s = 0;
    float4 w4 = make_float4(0.f, 0.f, 0.f, 0.f);
    if (l < cnt) {
      s = csrp[base + l];  // coalesced
      float4 a4 = *(const float4*)&as1[s * 4];
      w4.x = __expf(leaky02(a4.x + adn.x));
      w4.y = __expf(leaky02(a4.y + adn.y));
      w4.z = __expf(leaky02(a4.z + adn.z));
      w4.w = __expf(leaky02(a4.w + adn.w));
    }
    ldsS[wv][l] = s;
    *(float4*)&ldsW[wv][l][0] = w4;
    ds[0] += w4.x; ds[1] += w4.y; ds[2] += w4.z; ds[3] += w4.w;
    // gather: 8 edges/iter, 4 row-loads in flight per 32-lane group
    for (int j = 0; j < cnt; j += 8) {
      int e0 = j + g, e1 = j + 2 + g, e2 = j + 4 + g, e3 = j + 6 + g;  // all <= 63
      int s0 = ldsS[wv][e0], s1 = ldsS[wv][e1], s2 = ldsS[wv][e2], s3 = ldsS[wv][e3];
      float w0 = ldsW[wv][e0][hh], w1 = ldsW[wv][e1][hh];
      float w2 = ldsW[wv][e2][hh], w3 = ldsW[wv][e3][hh];
      ushort8 r0 = *(const ushort8*)&h1[(size_t)s0 * 256 + hoff];
      ushort8 r1 = *(const ushort8*)&h1[(size_t)s1 * 256 + hoff];
      ushort8 r2 = *(const ushort8*)&h1[(size_t)s2 * 256 + hoff];
      ushort8 r3 = *(const ushort8*)&h1[(size_t)s3 * 256 + hoff];
#pragma unroll
      for (int k = 0; k < 8; ++k) acc[k] = fmaf(w0, bf2f(r0[k]), acc[k]);
#pragma unroll
      for (int k = 0; k < 8; ++k) acc[k] = fmaf(w1, bf2f(r1[k]), acc[k]);
#pragma unroll
      for (int k = 0; k < 8; ++k) acc[k] = fmaf(w2, bf2f(r2[k]), acc[k]);
#pragma unroll
      for (int k = 0; k < 8; ++k) acc[k] = fmaf(w3, bf2f(r3[k]), acc[k]);
    }
  }
#pragma unroll
  for (int k = 0; k < 8; ++k) acc[k] += __shfl_xor(acc[k], 32, 64);
  float den[4];
#pragma unroll
  for (int h = 0; h < 4; ++h) den[h] = wave_sum(ds[h]);

  // self loop (weights computed inline)
  float4 asn = *(const float4*)&as1[n * 4];
  float wsf[4];
  wsf[0] = __expf(leaky02(asn.x + adn.x));
  wsf[1] = __expf(leaky02(asn.y + adn.y));
  wsf[2] = __expf(leaky02(asn.z + adn.z));
  wsf[3] = __expf(leaky02(asn.w + adn.w));
  ushort8 hn = *(const ushort8*)&h1[(size_t)n * 256 + hoff];
  float wsh = wsf[hh];
#pragma unroll
  for (int k = 0; k < 8; ++k) acc[k] = fmaf(wsh, bf2f(hn[k]), acc[k]);
  float inv = 1.f / (den[hh] + wsh + 1e-16f);

  int c0 = ll * 8 + g * 4;
  float4 Sv = *(const float4*)&S1[c0];
  float4 Tv = *(const float4*)&T1[c0];
  float Sf[4] = {Sv.x, Sv.y, Sv.z, Sv.w};
  float Tf[4] = {Tv.x, Tv.y, Tv.z, Tv.w};
  ushort4v o4;
#pragma unroll
  for (int q = 0; q < 4; ++q) {
    float o = fmaf(acc[g * 4 + q], inv * Sf[q], Tf[q]);
    o4[q] = f2bf(elu_fast(o));
  }
  *(ushort4v*)&out[(size_t)n * 256 + c0] = o4;
}

// ---------------- layer 2 agg: inline weights, 16 edges/iter, fused heads ----------------
__global__ __launch_bounds__(256) void agg2_kernel(
    const ushort_t* __restrict__ h2, const int* __restrict__ offsets,
    const int* __restrict__ csr, const float* __restrict__ as2,
    const float* __restrict__ ad2,
    const float* __restrict__ S2, const float* __restrict__ T2,
    const float* __restrict__ Wr, const float* __restrict__ br,
    const float* __restrict__ Wc, const float* __restrict__ bc,
    float* __restrict__ out_reg, float* __restrict__ out_clf, int N) {
  __shared__ float ldsW[4][64];
  __shared__ int ldsS[4][64];
  const int wv = threadIdx.x >> 6;
  int n = blockIdx.x * 4 + wv;
  int l = threadIdx.x & 63;
  if (n >= N) return;
  const int g = l >> 4, ll = l & 15;
  int off = offsets[n], deg = offsets[n + 1] - off;
  const int* csrp = csr + off;
  const size_t hoff = (size_t)ll * 4;
  float adn = ad2[n];

  float acc[4] = {0, 0, 0, 0};
  float ds = 0.f;

  for (int base = 0; base < deg; base += 64) {
    int cnt = min(64, deg - base);
    int s = 0;
    float wv_ = 0.f;
    if (l < cnt) {
      s = csrp[base + l];
      wv_ = __expf(leaky02(as2[s] + adn));
    }
    ldsS[wv][l] = s;
    ldsW[wv][l] = wv_;
    ds += wv_;
    for (int j = 0; j < cnt; j += 16) {
      int e0 = j + g, e1 = j + 4 + g, e2 = j + 8 + g, e3 = j + 12 + g;  // <= 63
      int s0 = ldsS[wv][e0], s1 = ldsS[wv][e1], s2 = ldsS[wv][e2], s3 = ldsS[wv][e3];
      float w0 = ldsW[wv][e0], w1 = ldsW[wv][e1], w2 = ldsW[wv][e2], w3 = ldsW[wv][e3];
      ushort4v r0 = *(const ushort4v*)&h2[(size_t)s0 * 64 + hoff];
      ushort4v r1 = *(const ushort4v*)&h2[(size_t)s1 * 64 + hoff];
      ushort4v r2 = *(const ushort4v*)&h2[(size_t)s2 * 64 + hoff];
      ushort4v r3 = *(const ushort4v*)&h2[(size_t)s3 * 64 + hoff];
#pragma unroll
      for (int k = 0; k < 4; ++k) acc[k] = fmaf(w0, bf2f(r0[k]), acc[k]);
#pragma unroll
      for (int k = 0; k < 4; ++k) acc[k] = fmaf(w1, bf2f(r1[k]), acc[k]);
#pragma unroll
      for (int k = 0; k < 4; ++k) acc[k] = fmaf(w2, bf2f(r2[k]), acc[k]);
#pragma unroll
      for (int k = 0; k < 4; ++k) acc[k] = fmaf(w3, bf2f(r3[k]), acc[k]);
    }
  }
#pragma unroll
  for (int k = 0; k < 4; ++k) {
    acc[k] += __shfl_xor(acc[k], 16, 64);
    acc[k] += __shfl_xor(acc[k], 32, 64);
  }
  float den = wave_sum(ds);
  float ws = __expf(leaky02(as2[n] + adn));
  ushort4v hn = *(const ushort4v*)&h2[(size_t)n * 64 + hoff];
#pragma unroll
  for (int k = 0; k < 4; ++k) acc[k] = fmaf(ws, bf2f(hn[k]), acc[k]);
  float inv = 1.f / (den + ws + 1e-16f);

  int c0 = ll * 4;
  float4 Sv = *(const float4*)&S2[c0];
  float4 Tv = *(const float4*)&T2[c0];
  float4 wr = *(const float4*)&Wr[c0];
  float4 wc = *(const float4*)&Wc[c0];
  float Sf[4] = {Sv.x, Sv.y, Sv.z, Sv.w};
  float Tf[4] = {Tv.x, Tv.y, Tv.z, Tv.w};
  float wrf[4] = {wr.x, wr.y, wr.z, wr.w};
  float wcf[4] = {wc.x, wc.y, wc.z, wc.w};
  float rs = 0.f, cs = 0.f;
#pragma unroll
  for (int q = 0; q < 4; ++q) {
    float o = fmaf(acc[q], inv * Sf[q], Tf[q]);
    o = elu_fast(o);
    rs = fmaf(o, wrf[q], rs);
    cs = fmaf(o, wcf[q], cs);
  }
#pragma unroll
  for (int o = 1; o < 16; o <<= 1) {
    rs += __shfl_xor(rs, o, 64);
    cs += __shfl_xor(cs, o, 64);
  }
  if (l == 0) {
    out_reg[n] = rs + br[0];
    float z = cs + bc[0];
    out_clf[n] = 1.f / (1.f + __expf(-z));
  }
}

// ---------------- launcher ----------------
extern "C" void kernel_launch(void* const* d_in, const int* in_sizes, int n_in,
                              void* d_out, int out_size, void* d_ws, size_t ws_size,
                              hipStream_t stream) {
  const float* x      = (const float*)d_in[0];
  const int*   ei     = (const int*)d_in[1];
  const float* W1     = (const float*)d_in[2];
  const float* a_src1 = (const float*)d_in[3];
  const float* a_dst1 = (const float*)d_in[4];
  const float* b1     = (const float*)d_in[5];
  const float* bn1w   = (const float*)d_in[6];
  const float* bn1b   = (const float*)d_in[7];
  const float* bn1m   = (const float*)d_in[8];
  const float* bn1v   = (const float*)d_in[9];
  const float* W2     = (const float*)d_in[10];
  const float* a_src2 = (const float*)d_in[11];
  const float* a_dst2 = (const float*)d_in[12];
  const float* b2     = (const float*)d_in[13];
  const float* bn2w   = (const float*)d_in[14];
  const float* bn2b   = (const float*)d_in[15];
  const float* bn2m   = (const float*)d_in[16];
  const float* bn2v   = (const float*)d_in[17];
  const float* Wr     = (const float*)d_in[18];
  const float* br     = (const float*)d_in[19];
  const float* Wc     = (const float*)d_in[20];
  const float* bc     = (const float*)d_in[21];

  const int N = in_sizes[0] / 256;  // 50000
  const int E = in_sizes[1] / 2;    // 400000
  const int* srcv = ei;
  const int* dstv = ei + E;

  char* w = (char*)d_ws;
  auto alloc = [&](size_t bytes) {
    char* p = w;
    w += (bytes + 255) & ~(size_t)255;
    return p;
  };
  int* counts    = (int*)alloc((size_t)N * 4);
  int* cursor    = (int*)alloc((size_t)N * 4);
  int* offsets   = (int*)alloc((size_t)(N + 1) * 4);
  int* partials  = (int*)alloc(2048 * 4);
  int* pprefix   = (int*)alloc(2049 * 4);
  int* csr_src   = (int*)alloc((size_t)(E + 64) * 4);  // +64 zero pad
  float* as1     = (float*)alloc((size_t)N * 4 * 4);
  float* ad1     = (float*)alloc((size_t)N * 4 * 4);
  float* as2     = (float*)alloc((size_t)N * 4);
  float* ad2     = (float*)alloc((size_t)N * 4);
  float* S1      = (float*)alloc(256 * 4);
  float* T1      = (float*)alloc(256 * 4);
  float* S2      = (float*)alloc(64 * 4);
  float* T2      = (float*)alloc(64 * 4);
  ushort_t* W1t  = (ushort_t*)alloc((size_t)256 * 256 * 2);
  ushort_t* W2t  = (ushort_t*)alloc((size_t)64 * 256 * 2);
  ushort_t* h1b  = (ushort_t*)alloc((size_t)N * 256 * 2);
  ushort_t* h1a  = (ushort_t*)alloc((size_t)N * 256 * 2);
  ushort_t* h2b  = (ushort_t*)alloc((size_t)N * 64 * 2);

  float* out_reg = (float*)d_out;

  // cooperative graph build at full occupancy; fallback chain if too large
  BuildArgs ba;
  ba.src = srcv; ba.dst = dstv; ba.E = E; ba.N = N;
  ba.counts = counts; ba.cursor = cursor; ba.offsets = offsets;
  ba.partials = partials; ba.pprefix = pprefix; ba.csr_src = csr_src;
  ba.W1 = W1; ba.W2 = W2; ba.W1t = W1t; ba.W2t = W2t;
  ba.b1 = b1; ba.bn1w = bn1w; ba.bn1b = bn1b; ba.bn1m = bn1m; ba.bn1v = bn1v;
  ba.b2 = b2; ba.bn2w = bn2w; ba.bn2b = bn2b; ba.bn2m = bn2m; ba.bn2v = bn2v;
  ba.S1 = S1; ba.T1 = T1; ba.S2 = S2; ba.T2 = T2;
  const int grids[3] = {2048, 1024, 256};
  for (int gi = 0; gi < 3; ++gi) {
    ba.CH = (N + grids[gi] - 1) / grids[gi];
    void* kargs[] = {(void*)&ba};
    hipError_t err = hipLaunchCooperativeKernel((void*)build_kernel, dim3(grids[gi]),
                                                dim3(256), kargs, 0, stream);
    if (err == hipSuccess) break;
  }

  const int nwb = (N + 3) / 4;

  // layer 1
  dim3 g1(4, (N + 127) / 128);
  mfma_gemm_fused<4, true><<<g1, 256, 0, stream>>>(x, W1t, h1b, a_src1, a_dst1, as1, ad1,
                                                   N, 256, 256, 4);
  agg1_kernel<<<nwb, 256, 0, stream>>>(h1b, offsets, csr_src, as1, ad1, S1, T1, h1a, N);

  // layer 2
  dim3 g2(1, (N + 63) / 64);
  mfma_gemm_fused<2, false><<<g2, 128, 0, stream>>>(h1a, W2t, h2b, a_src2, a_dst2, as2, ad2,
                                                    N, 64, 256, 1);
  agg2_kernel<<<nwb, 256, 0, stream>>>(h2b, offsets, csr_src, as2, ad2, S2, T2,
                                       Wr, br, Wc, bc, out_reg, out_reg + N, N);
}

// Round 8
// 282.590 us; speedup vs baseline: 4.6937x; 4.6937x over previous
//
#include <hip/hip_runtime.h>
#include <math.h>

// MultiTaskGNN: 2-layer GAT + BN + ELU + two heads. N=50000, E=400000.
// R8: discrete-dispatch graph build (cooperative grid.sync abandoned: ~180us
// per sync at 2048 blocks). 9 dispatches: memset, hist, scan_chunks(+W/BN
// prep), scan_partials, scatter(+offset finalize), gemm1, agg1, gemm2, agg2.
// Agg kernels: R7's inline-weight wave-local-LDS versions (proven).

typedef unsigned short ushort_t;
typedef __attribute__((ext_vector_type(8))) unsigned short ushort8;
typedef __attribute__((ext_vector_type(4))) unsigned short ushort4v;
typedef __attribute__((ext_vector_type(8))) short short8;
typedef __attribute__((ext_vector_type(4))) float f32x4;

#define EPS_BN 1e-5f

__device__ __forceinline__ ushort_t f2bf(float f) {  // RNE
  unsigned u = __float_as_uint(f);
  unsigned r = u + 0x7fffu + ((u >> 16) & 1u);
  return (ushort_t)(r >> 16);
}
__device__ __forceinline__ float bf2f(ushort_t h) {
  return __uint_as_float((unsigned)h << 16);
}
__device__ __forceinline__ float leaky02(float x) { return x >= 0.f ? x : 0.2f * x; }
__device__ __forceinline__ float elu_fast(float x) {
  return x > 0.f ? x : __expf(x) - 1.f;
}
__device__ __forceinline__ float wave_sum(float v) {
#pragma unroll
  for (int o = 1; o < 64; o <<= 1) v += __shfl_xor(v, o, 64);
  return v;
}
__device__ __forceinline__ int wave_incl_scan(int v, int lane) {
#pragma unroll
  for (int off = 1; off < 64; off <<= 1) {
    int t = __shfl_up(v, off, 64);
    if (lane >= off) v += t;
  }
  return v;
}

__device__ __forceinline__ void gld_lds16(const ushort_t* g, ushort_t* l) {
  __builtin_amdgcn_global_load_lds(
      (const __attribute__((address_space(1))) unsigned int*)g,
      (__attribute__((address_space(3))) unsigned int*)l, 16, 0, 0);
}

// ---------------- hist ----------------
__global__ void hist_kernel(const int* __restrict__ dst, int* __restrict__ counts, int E) {
  int e = blockIdx.x * blockDim.x + threadIdx.x;
  if (e < E) atomicAdd(&counts[dst[e]], 1);
}

// ---------------- scan chunks (256/block) + merged prep work ----------------
__global__ __launch_bounds__(256) void scan_chunks_kernel(
    const int* __restrict__ counts, int* __restrict__ offsets, int* __restrict__ partials,
    int N, int E, int* __restrict__ csr_src,
    const float* __restrict__ W1, const float* __restrict__ W2,
    ushort_t* __restrict__ W1t, ushort_t* __restrict__ W2t,
    const float* __restrict__ b1, const float* __restrict__ bn1w,
    const float* __restrict__ bn1b, const float* __restrict__ bn1m,
    const float* __restrict__ bn1v,
    const float* __restrict__ b2, const float* __restrict__ bn2w,
    const float* __restrict__ bn2b, const float* __restrict__ bn2m,
    const float* __restrict__ bn2v,
    float* __restrict__ S1, float* __restrict__ T1,
    float* __restrict__ S2, float* __restrict__ T2) {
  __shared__ int ws[4];
  const int tid = threadIdx.x, lane = tid & 63, wv = tid >> 6;
  const int i = blockIdx.x * 256 + tid;
  const int gsz = gridDim.x * 256;
  int v = (i < N) ? counts[i] : 0;
  int incl = wave_incl_scan(v, lane);
  if (lane == 63) ws[wv] = incl;
  __syncthreads();
  int wbase = 0;
  for (int k = 0; k < wv; ++k) wbase += ws[k];
  if (i < N) offsets[i] = wbase + incl - v;  // chunk-local exclusive
  if (tid == 255) partials[blockIdx.x] = wbase + incl;

  // merged prep (independent work)
  for (int j = i; j < 256 * 256; j += gsz) {
    int k = j >> 8, n2 = j & 255;
    W1t[n2 * 256 + k] = f2bf(W1[j]);
  }
  for (int j = i; j < 256 * 64; j += gsz) {
    int k = j >> 6, n2 = j & 63;
    W2t[n2 * 256 + k] = f2bf(W2[j]);
  }
  if (i < 256) {
    float s = bn1w[i] * rsqrtf(bn1v[i] + EPS_BN);
    S1[i] = s;
    T1[i] = (b1[i] - bn1m[i]) * s + bn1b[i];
  } else if (i < 320) {
    int j = i - 256;
    float s = bn2w[j] * rsqrtf(bn2v[j] + EPS_BN);
    S2[j] = s;
    T2[j] = (b2[j] - bn2m[j]) * s + bn2b[j];
  } else if (i < 384) {
    csr_src[E + i - 320] = 0;  // zero pad for unclamped tail loads
  }
}

// ---------------- scan partials (1 block) ----------------
__global__ __launch_bounds__(256) void scan_partials_kernel(const int* __restrict__ partials,
                                                            int* __restrict__ pprefix, int nb) {
  __shared__ int ws[4];
  int tid = threadIdx.x, lane = tid & 63, wv = tid >> 6;
  int v = (tid < nb) ? partials[tid] : 0;
  int incl = wave_incl_scan(v, lane);
  if (lane == 63) ws[wv] = incl;
  __syncthreads();
  int wbase = 0;
  for (int k = 0; k < wv; ++k) wbase += ws[k];
  if (tid < nb) pprefix[tid] = wbase + incl - v;
  if (tid == 255) pprefix[nb] = wbase + incl;  // grand total = E
}

// ---------------- scatter + finalize offsets ----------------
__global__ void scatter_kernel(const int* __restrict__ src, const int* __restrict__ dst,
                               const int* __restrict__ offsets, const int* __restrict__ pprefix,
                               int* __restrict__ cursor, int* __restrict__ csr_src,
                               int* __restrict__ offs2, int E, int N, int nb) {
  int idx = blockIdx.x * blockDim.x + threadIdx.x;
  if (idx < E) {
    int d = dst[idx];
    int p = atomicAdd(&cursor[d], 1);
    csr_src[offsets[d] + pprefix[d >> 8] + p] = src[idx];
  }
  if (idx <= N) {
    offs2[idx] = (idx < N) ? offsets[idx] + pprefix[idx >> 8] : pprefix[nb];
  }
}

// ---------------- MFMA bf16 GEMM + fused alpha epilogue ----------------
template <int WM, bool CASTA>
__global__ __launch_bounds__(WM * 64) void mfma_gemm_fused(
    const void* __restrict__ Ain, const ushort_t* __restrict__ Bt,
    ushort_t* __restrict__ C, const float* __restrict__ avs, const float* __restrict__ avd,
    float* __restrict__ as_out, float* __restrict__ ad_out, int M, int Nt, int K, int H) {
  constexpr int BM = WM * 32;
  constexpr int NB = 4 / WM;
  __shared__ ushort_t As[BM * 32];
  __shared__ ushort_t Bs[64 * 32];
  const int t = threadIdx.x;
  const int w = t >> 6, l = t & 63;
  const int m0 = blockIdx.y * BM;
  const int n0 = blockIdx.x * 64;
  const int head = n0 >> 6;

  f32x4 zero4 = {0.f, 0.f, 0.f, 0.f};
  f32x4 acc[2][4];
#pragma unroll
  for (int i = 0; i < 2; ++i)
#pragma unroll
    for (int j = 0; j < 4; ++j) acc[i][j] = zero4;

  const int scol = (l & 3) * 8;
  const ushort_t* Bgb[NB];
  ushort_t* Bsl[NB];
#pragma unroll
  for (int b = 0; b < NB; ++b) {
    int r = (b * WM + w) * 16 + (l >> 2);
    Bgb[b] = Bt + (size_t)(n0 + r) * K + scol;
    Bsl[b] = &Bs[(b * WM + w) * 512];
  }
  const ushort_t* Aga[2];
  ushort_t* Asl[2];
  const float* Axg = nullptr;
  ushort_t* AsWc = nullptr;
  if (CASTA) {
    int ar = t >> 1, ac = (t & 1) * 16;
    Axg = (const float*)Ain + (size_t)min(m0 + ar, M - 1) * K + ac;
    AsWc = &As[ar * 32 + ac];
  } else {
#pragma unroll
    for (int a = 0; a < 2; ++a) {
      int r = (a * WM + w) * 16 + (l >> 2);
      int gr = min(m0 + r, M - 1);
      Aga[a] = (const ushort_t*)Ain + (size_t)gr * K + scol;
      Asl[a] = &As[(a * WM + w) * 512];
    }
  }

  for (int k0 = 0; k0 < K; k0 += 32) {
    if (CASTA) {
      float4 f0 = *(const float4*)(Axg + k0);
      float4 f1 = *(const float4*)(Axg + k0 + 4);
      float4 f2 = *(const float4*)(Axg + k0 + 8);
      float4 f3 = *(const float4*)(Axg + k0 + 12);
      __syncthreads();
#pragma unroll
      for (int b = 0; b < NB; ++b) gld_lds16(Bgb[b] + k0, Bsl[b]);
      ushort8 u0, u1;
      u0[0] = f2bf(f0.x); u0[1] = f2bf(f0.y); u0[2] = f2bf(f0.z); u0[3] = f2bf(f0.w);
      u0[4] = f2bf(f1.x); u0[5] = f2bf(f1.y); u0[6] = f2bf(f1.z); u0[7] = f2bf(f1.w);
      u1[0] = f2bf(f2.x); u1[1] = f2bf(f2.y); u1[2] = f2bf(f2.z); u1[3] = f2bf(f2.w);
      u1[4] = f2bf(f3.x); u1[5] = f2bf(f3.y); u1[6] = f2bf(f3.z); u1[7] = f2bf(f3.w);
      *(ushort8*)AsWc = u0;
      *(ushort8*)(AsWc + 8) = u1;
      __syncthreads();
    } else {
      __syncthreads();
#pragma unroll
      for (int a = 0; a < 2; ++a) gld_lds16(Aga[a] + k0, Asl[a]);
#pragma unroll
      for (int b = 0; b < NB; ++b) gld_lds16(Bgb[b] + k0, Bsl[b]);
      __syncthreads();
    }
    const int kq = (l >> 4) * 8;
    short8 af[2], bfr[4];
#pragma unroll
    for (int i = 0; i < 2; ++i)
      af[i] = *(const short8*)&As[(w * 32 + i * 16 + (l & 15)) * 32 + kq];
#pragma unroll
    for (int j = 0; j < 4; ++j)
      bfr[j] = *(const short8*)&Bs[(j * 16 + (l & 15)) * 32 + kq];
#pragma unroll
    for (int i = 0; i < 2; ++i)
#pragma unroll
      for (int j = 0; j < 4; ++j)
        acc[i][j] = __builtin_amdgcn_mfma_f32_16x16x32_bf16(af[i], bfr[j], acc[i][j], 0, 0, 0);
  }

  const int rbase = m0 + w * 32 + (l >> 4) * 4;
  const int cbase = n0 + (l & 15);
#pragma unroll
  for (int i = 0; i < 2; ++i)
#pragma unroll
    for (int j = 0; j < 4; ++j)
#pragma unroll
      for (int r = 0; r < 4; ++r) {
        int row = rbase + i * 16 + r;
        if (row < M) C[(size_t)row * Nt + cbase + j * 16] = f2bf(acc[i][j][r]);
      }

  float asw[4], adw[4];
#pragma unroll
  for (int j = 0; j < 4; ++j) {
    asw[j] = avs[head * 64 + (l & 15) + j * 16];
    adw[j] = avd[head * 64 + (l & 15) + j * 16];
  }
#pragma unroll
  for (int i = 0; i < 2; ++i)
#pragma unroll
    for (int r = 0; r < 4; ++r) {
      float s_ = acc[i][0][r] * asw[0] + acc[i][1][r] * asw[1] +
                 acc[i][2][r] * asw[2] + acc[i][3][r] * asw[3];
      float d_ = acc[i][0][r] * adw[0] + acc[i][1][r] * adw[1] +
                 acc[i][2][r] * adw[2] + acc[i][3][r] * adw[3];
#pragma unroll
      for (int o = 1; o < 16; o <<= 1) {
        s_ += __shfl_xor(s_, o, 64);
        d_ += __shfl_xor(d_, o, 64);
      }
      if ((l & 15) == 0) {
        int row = rbase + i * 16 + r;
        if (row < M) {
          as_out[(size_t)row * H + head] = s_;
          ad_out[(size_t)row * H + head] = d_;
        }
      }
    }
}

// ---------------- layer 1 agg: inline weights via wave-local LDS ----------------
__global__ __launch_bounds__(256) void agg1_kernel(
    const ushort_t* __restrict__ h1, const int* __restrict__ offsets,
    const int* __restrict__ csr, const float* __restrict__ as1,
    const float* __restrict__ ad1,
    const float* __restrict__ S1, const float* __restrict__ T1,
    ushort_t* __restrict__ out, int N) {
  __shared__ float ldsW[4][64][4];
  __shared__ int ldsS[4][64];
  const int wv = threadIdx.x >> 6;
  int n = blockIdx.x * 4 + wv;
  int l = threadIdx.x & 63;
  if (n >= N) return;
  const int g = l >> 5, ll = l & 31, hh = ll >> 3;
  int off = offsets[n], deg = offsets[n + 1] - off;
  const int* csrp = csr + off;
  const size_t hoff = (size_t)ll * 8;
  float4 adn = *(const float4*)&ad1[n * 4];

  float acc[8] = {0, 0, 0, 0, 0, 0, 0, 0};
  float ds[4] = {0, 0, 0, 0};

  for (int base = 0; base < deg; base += 64) {
    int cnt = min(64, deg - base);
    int s = 0;
    float4 w4 = make_float4(0.f, 0.f, 0.f, 0.f);
    if (l < cnt) {
      s = csrp[base + l];  // coalesced
      float4 a4 = *(const float4*)&as1[s * 4];
      w4.x = __expf(leaky02(a4.x + adn.x));
      w4.y = __expf(leaky02(a4.y + adn.y));
      w4.z = __expf(leaky02(a4.z + adn.z));
      w4.w = __expf(leaky02(a4.w + adn.w));
    }
    ldsS[wv][l] = s;
    *(float4*)&ldsW[wv][l][0] = w4;
    ds[0] += w4.x; ds[1] += w4.y; ds[2] += w4.z; ds[3] += w4.w;
    for (int j = 0; j < cnt; j += 8) {
      int e0 = j + g, e1 = j + 2 + g, e2 = j + 4 + g, e3 = j + 6 + g;  // all <= 63
      int s0 = ldsS[wv][e0], s1 = ldsS[wv][e1], s2 = ldsS[wv][e2], s3 = ldsS[wv][e3];
      float w0 = ldsW[wv][e0][hh], w1 = ldsW[wv][e1][hh];
      float w2 = ldsW[wv][e2][hh], w3 = ldsW[wv][e3][hh];
      ushort8 r0 = *(const ushort8*)&h1[(size_t)s0 * 256 + hoff];
      ushort8 r1 = *(const ushort8*)&h1[(size_t)s1 * 256 + hoff];
      ushort8 r2 = *(const ushort8*)&h1[(size_t)s2 * 256 + hoff];
      ushort8 r3 = *(const ushort8*)&h1[(size_t)s3 * 256 + hoff];
#pragma unroll
      for (int k = 0; k < 8; ++k) acc[k] = fmaf(w0, bf2f(r0[k]), acc[k]);
#pragma unroll
      for (int k = 0; k < 8; ++k) acc[k] = fmaf(w1, bf2f(r1[k]), acc[k]);
#pragma unroll
      for (int k = 0; k < 8; ++k) acc[k] = fmaf(w2, bf2f(r2[k]), acc[k]);
#pragma unroll
      for (int k = 0; k < 8; ++k) acc[k] = fmaf(w3, bf2f(r3[k]), acc[k]);
    }
  }
#pragma unroll
  for (int k = 0; k < 8; ++k) acc[k] += __shfl_xor(acc[k], 32, 64);
  float den[4];
#pragma unroll
  for (int h = 0; h < 4; ++h) den[h] = wave_sum(ds[h]);

  float4 asn = *(const float4*)&as1[n * 4];
  float wsf[4];
  wsf[0] = __expf(leaky02(asn.x + adn.x));
  wsf[1] = __expf(leaky02(asn.y + adn.y));
  wsf[2] = __expf(leaky02(asn.z + adn.z));
  wsf[3] = __expf(leaky02(asn.w + adn.w));
  ushort8 hn = *(const ushort8*)&h1[(size_t)n * 256 + hoff];
  float wsh = wsf[hh];
#pragma unroll
  for (int k = 0; k < 8; ++k) acc[k] = fmaf(wsh, bf2f(hn[k]), acc[k]);
  float inv = 1.f / (den[hh] + wsh + 1e-16f);

  int c0 = ll * 8 + g * 4;
  float4 Sv = *(const float4*)&S1[c0];
  float4 Tv = *(const float4*)&T1[c0];
  float Sf[4] = {Sv.x, Sv.y, Sv.z, Sv.w};
  float Tf[4] = {Tv.x, Tv.y, Tv.z, Tv.w};
  ushort4v o4;
#pragma unroll
  for (int q = 0; q < 4; ++q) {
    float o = fmaf(acc[g * 4 + q], inv * Sf[q], Tf[q]);
    o4[q] = f2bf(elu_fast(o));
  }
  *(ushort4v*)&out[(size_t)n * 256 + c0] = o4;
}

// ---------------- layer 2 agg: inline weights, 16 edges/iter, fused heads ----------------
__global__ __launch_bounds__(256) void agg2_kernel(
    const ushort_t* __restrict__ h2, const int* __restrict__ offsets,
    const int* __restrict__ csr, const float* __restrict__ as2,
    const float* __restrict__ ad2,
    const float* __restrict__ S2, const float* __restrict__ T2,
    const float* __restrict__ Wr, const float* __restrict__ br,
    const float* __restrict__ Wc, const float* __restrict__ bc,
    float* __restrict__ out_reg, float* __restrict__ out_clf, int N) {
  __shared__ float ldsW[4][64];
  __shared__ int ldsS[4][64];
  const int wv = threadIdx.x >> 6;
  int n = blockIdx.x * 4 + wv;
  int l = threadIdx.x & 63;
  if (n >= N) return;
  const int g = l >> 4, ll = l & 15;
  int off = offsets[n], deg = offsets[n + 1] - off;
  const int* csrp = csr + off;
  const size_t hoff = (size_t)ll * 4;
  float adn = ad2[n];

  float acc[4] = {0, 0, 0, 0};
  float ds = 0.f;

  for (int base = 0; base < deg; base += 64) {
    int cnt = min(64, deg - base);
    int s = 0;
    float wv_ = 0.f;
    if (l < cnt) {
      s = csrp[base + l];
      wv_ = __expf(leaky02(as2[s] + adn));
    }
    ldsS[wv][l] = s;
    ldsW[wv][l] = wv_;
    ds += wv_;
    for (int j = 0; j < cnt; j += 16) {
      int e0 = j + g, e1 = j + 4 + g, e2 = j + 8 + g, e3 = j + 12 + g;  // <= 63
      int s0 = ldsS[wv][e0], s1 = ldsS[wv][e1], s2 = ldsS[wv][e2], s3 = ldsS[wv][e3];
      float w0 = ldsW[wv][e0], w1 = ldsW[wv][e1], w2 = ldsW[wv][e2], w3 = ldsW[wv][e3];
      ushort4v r0 = *(const ushort4v*)&h2[(size_t)s0 * 64 + hoff];
      ushort4v r1 = *(const ushort4v*)&h2[(size_t)s1 * 64 + hoff];
      ushort4v r2 = *(const ushort4v*)&h2[(size_t)s2 * 64 + hoff];
      ushort4v r3 = *(const ushort4v*)&h2[(size_t)s3 * 64 + hoff];
#pragma unroll
      for (int k = 0; k < 4; ++k) acc[k] = fmaf(w0, bf2f(r0[k]), acc[k]);
#pragma unroll
      for (int k = 0; k < 4; ++k) acc[k] = fmaf(w1, bf2f(r1[k]), acc[k]);
#pragma unroll
      for (int k = 0; k < 4; ++k) acc[k] = fmaf(w2, bf2f(r2[k]), acc[k]);
#pragma unroll
      for (int k = 0; k < 4; ++k) acc[k] = fmaf(w3, bf2f(r3[k]), acc[k]);
    }
  }
#pragma unroll
  for (int k = 0; k < 4; ++k) {
    acc[k] += __shfl_xor(acc[k], 16, 64);
    acc[k] += __shfl_xor(acc[k], 32, 64);
  }
  float den = wave_sum(ds);
  float ws = __expf(leaky02(as2[n] + adn));
  ushort4v hn = *(const ushort4v*)&h2[(size_t)n * 64 + hoff];
#pragma unroll
  for (int k = 0; k < 4; ++k) acc[k] = fmaf(ws, bf2f(hn[k]), acc[k]);
  float inv = 1.f / (den + ws + 1e-16f);

  int c0 = ll * 4;
  float4 Sv = *(const float4*)&S2[c0];
  float4 Tv = *(const float4*)&T2[c0];
  float4 wr = *(const float4*)&Wr[c0];
  float4 wc = *(const float4*)&Wc[c0];
  float Sf[4] = {Sv.x, Sv.y, Sv.z, Sv.w};
  float Tf[4] = {Tv.x, Tv.y, Tv.z, Tv.w};
  float wrf[4] = {wr.x, wr.y, wr.z, wr.w};
  float wcf[4] = {wc.x, wc.y, wc.z, wc.w};
  float rs = 0.f, cs = 0.f;
#pragma unroll
  for (int q = 0; q < 4; ++q) {
    float o = fmaf(acc[q], inv * Sf[q], Tf[q]);
    o = elu_fast(o);
    rs = fmaf(o, wrf[q], rs);
    cs = fmaf(o, wcf[q], cs);
  }
#pragma unroll
  for (int o = 1; o < 16; o <<= 1) {
    rs += __shfl_xor(rs, o, 64);
    cs += __shfl_xor(cs, o, 64);
  }
  if (l == 0) {
    out_reg[n] = rs + br[0];
    float z = cs + bc[0];
    out_clf[n] = 1.f / (1.f + __expf(-z));
  }
}

// ---------------- launcher ----------------
extern "C" void kernel_launch(void* const* d_in, const int* in_sizes, int n_in,
                              void* d_out, int out_size, void* d_ws, size_t ws_size,
                              hipStream_t stream) {
  const float* x      = (const float*)d_in[0];
  const int*   ei     = (const int*)d_in[1];
  const float* W1     = (const float*)d_in[2];
  const float* a_src1 = (const float*)d_in[3];
  const float* a_dst1 = (const float*)d_in[4];
  const float* b1     = (const float*)d_in[5];
  const float* bn1w   = (const float*)d_in[6];
  const float* bn1b   = (const float*)d_in[7];
  const float* bn1m   = (const float*)d_in[8];
  const float* bn1v   = (const float*)d_in[9];
  const float* W2     = (const float*)d_in[10];
  const float* a_src2 = (const float*)d_in[11];
  const float* a_dst2 = (const float*)d_in[12];
  const float* b2     = (const float*)d_in[13];
  const float* bn2w   = (const float*)d_in[14];
  const float* bn2b   = (const float*)d_in[15];
  const float* bn2m   = (const float*)d_in[16];
  const float* bn2v   = (const float*)d_in[17];
  const float* Wr     = (const float*)d_in[18];
  const float* br     = (const float*)d_in[19];
  const float* Wc     = (const float*)d_in[20];
  const float* bc     = (const float*)d_in[21];

  const int N = in_sizes[0] / 256;  // 50000
  const int E = in_sizes[1] / 2;    // 400000
  const int* srcv = ei;
  const int* dstv = ei + E;

  char* w = (char*)d_ws;
  auto alloc = [&](size_t bytes) {
    char* p = w;
    w += (bytes + 255) & ~(size_t)255;
    return p;
  };
  const int nb = (N + 255) / 256;  // 196 chunks of 256
  const size_t nbytes_rounded = ((size_t)N * 4 + 255) & ~(size_t)255;
  int* counts    = (int*)alloc((size_t)N * 4);
  int* cursor    = (int*)alloc((size_t)N * 4);  // contiguous with counts
  int* offsets   = (int*)alloc((size_t)N * 4);  // chunk-local scan
  int* offs2     = (int*)alloc((size_t)(N + 1) * 4);  // finalized
  int* partials  = (int*)alloc((size_t)nb * 4);
  int* pprefix   = (int*)alloc((size_t)(nb + 1) * 4);
  int* csr_src   = (int*)alloc((size_t)(E + 64) * 4);  // +64 zero pad
  float* as1     = (float*)alloc((size_t)N * 4 * 4);
  float* ad1     = (float*)alloc((size_t)N * 4 * 4);
  float* as2     = (float*)alloc((size_t)N * 4);
  float* ad2     = (float*)alloc((size_t)N * 4);
  float* S1      = (float*)alloc(256 * 4);
  float* T1      = (float*)alloc(256 * 4);
  float* S2      = (float*)alloc(64 * 4);
  float* T2      = (float*)alloc(64 * 4);
  ushort_t* W1t  = (ushort_t*)alloc((size_t)256 * 256 * 2);
  ushort_t* W2t  = (ushort_t*)alloc((size_t)64 * 256 * 2);
  ushort_t* h1b  = (ushort_t*)alloc((size_t)N * 256 * 2);
  ushort_t* h1a  = (ushort_t*)alloc((size_t)N * 256 * 2);
  ushort_t* h2b  = (ushort_t*)alloc((size_t)N * 64 * 2);

  float* out_reg = (float*)d_out;

  // graph build (5 cheap dispatches)
  hipMemsetAsync(counts, 0, nbytes_rounded * 2, stream);  // counts + cursor
  hist_kernel<<<(E + 255) / 256, 256, 0, stream>>>(dstv, counts, E);
  scan_chunks_kernel<<<nb, 256, 0, stream>>>(counts, offsets, partials, N, E, csr_src,
                                             W1, W2, W1t, W2t,
                                             b1, bn1w, bn1b, bn1m, bn1v,
                                             b2, bn2w, bn2b, bn2m, bn2v,
                                             S1, T1, S2, T2);
  scan_partials_kernel<<<1, 256, 0, stream>>>(partials, pprefix, nb);
  {
    int items = max(E, N + 1);
    scatter_kernel<<<(items + 255) / 256, 256, 0, stream>>>(srcv, dstv, offsets, pprefix,
                                                            cursor, csr_src, offs2, E, N, nb);
  }

  const int nwb = (N + 3) / 4;

  // layer 1
  dim3 g1(4, (N + 127) / 128);
  mfma_gemm_fused<4, true><<<g1, 256, 0, stream>>>(x, W1t, h1b, a_src1, a_dst1, as1, ad1,
                                                   N, 256, 256, 4);
  agg1_kernel<<<nwb, 256, 0, stream>>>(h1b, offs2, csr_src, as1, ad1, S1, T1, h1a, N);

  // layer 2
  dim3 g2(1, (N + 63) / 64);
  mfma_gemm_fused<2, false><<<g2, 128, 0, stream>>>(h1a, W2t, h2b, a_src2, a_dst2, as2, ad2,
                                                    N, 64, 256, 1);
  agg2_kernel<<<nwb, 256, 0, stream>>>(h2b, offs2, csr_src, as2, ad2, S2, T2,
                                       Wr, br, Wc, bc, out_reg, out_reg + N, N);
}

// Round 9
// 271.494 us; speedup vs baseline: 4.8856x; 1.0409x over previous
//
#include <hip/hip_runtime.h>
#include <math.h>

// MultiTaskGNN: 2-layer GAT + BN + ELU + two heads. N=50000, E=400000.
// R9: scan_partials folded into scatter (8 dispatches), gemm1 XCD-sibling
// swizzle (4 head-blocks of a row-tile -> same XCD for L2 reuse of x).
// agg kernels unchanged from R8 (proven 49us agg1).

typedef unsigned short ushort_t;
typedef __attribute__((ext_vector_type(8))) unsigned short ushort8;
typedef __attribute__((ext_vector_type(4))) unsigned short ushort4v;
typedef __attribute__((ext_vector_type(8))) short short8;
typedef __attribute__((ext_vector_type(4))) float f32x4;

#define EPS_BN 1e-5f

__device__ __forceinline__ ushort_t f2bf(float f) {  // RNE
  unsigned u = __float_as_uint(f);
  unsigned r = u + 0x7fffu + ((u >> 16) & 1u);
  return (ushort_t)(r >> 16);
}
__device__ __forceinline__ float bf2f(ushort_t h) {
  return __uint_as_float((unsigned)h << 16);
}
__device__ __forceinline__ float leaky02(float x) { return x >= 0.f ? x : 0.2f * x; }
__device__ __forceinline__ float elu_fast(float x) {
  return x > 0.f ? x : __expf(x) - 1.f;
}
__device__ __forceinline__ float wave_sum(float v) {
#pragma unroll
  for (int o = 1; o < 64; o <<= 1) v += __shfl_xor(v, o, 64);
  return v;
}
__device__ __forceinline__ int wave_incl_scan(int v, int lane) {
#pragma unroll
  for (int off = 1; off < 64; off <<= 1) {
    int t = __shfl_up(v, off, 64);
    if (lane >= off) v += t;
  }
  return v;
}

__device__ __forceinline__ void gld_lds16(const ushort_t* g, ushort_t* l) {
  __builtin_amdgcn_global_load_lds(
      (const __attribute__((address_space(1))) unsigned int*)g,
      (__attribute__((address_space(3))) unsigned int*)l, 16, 0, 0);
}

// ---------------- hist ----------------
__global__ void hist_kernel(const int* __restrict__ dst, int* __restrict__ counts, int E) {
  int e = blockIdx.x * blockDim.x + threadIdx.x;
  if (e < E) atomicAdd(&counts[dst[e]], 1);
}

// ---------------- scan chunks (256/block) + merged prep work ----------------
__global__ __launch_bounds__(256) void scan_chunks_kernel(
    const int* __restrict__ counts, int* __restrict__ offsets, int* __restrict__ partials,
    int N, int E, int* __restrict__ csr_src,
    const float* __restrict__ W1, const float* __restrict__ W2,
    ushort_t* __restrict__ W1t, ushort_t* __restrict__ W2t,
    const float* __restrict__ b1, const float* __restrict__ bn1w,
    const float* __restrict__ bn1b, const float* __restrict__ bn1m,
    const float* __restrict__ bn1v,
    const float* __restrict__ b2, const float* __restrict__ bn2w,
    const float* __restrict__ bn2b, const float* __restrict__ bn2m,
    const float* __restrict__ bn2v,
    float* __restrict__ S1, float* __restrict__ T1,
    float* __restrict__ S2, float* __restrict__ T2) {
  __shared__ int ws[4];
  const int tid = threadIdx.x, lane = tid & 63, wv = tid >> 6;
  const int i = blockIdx.x * 256 + tid;
  const int gsz = gridDim.x * 256;
  int v = (i < N) ? counts[i] : 0;
  int incl = wave_incl_scan(v, lane);
  if (lane == 63) ws[wv] = incl;
  __syncthreads();
  int wbase = 0;
  for (int k = 0; k < wv; ++k) wbase += ws[k];
  if (i < N) offsets[i] = wbase + incl - v;  // chunk-local exclusive
  if (tid == 255) partials[blockIdx.x] = wbase + incl;

  // merged prep (independent work)
  for (int j = i; j < 256 * 256; j += gsz) {
    int k = j >> 8, n2 = j & 255;
    W1t[n2 * 256 + k] = f2bf(W1[j]);
  }
  for (int j = i; j < 256 * 64; j += gsz) {
    int k = j >> 6, n2 = j & 63;
    W2t[n2 * 256 + k] = f2bf(W2[j]);
  }
  if (i < 256) {
    float s = bn1w[i] * rsqrtf(bn1v[i] + EPS_BN);
    S1[i] = s;
    T1[i] = (b1[i] - bn1m[i]) * s + bn1b[i];
  } else if (i < 320) {
    int j = i - 256;
    float s = bn2w[j] * rsqrtf(bn2v[j] + EPS_BN);
    S2[j] = s;
    T2[j] = (b2[j] - bn2m[j]) * s + bn2b[j];
  } else if (i < 384) {
    csr_src[E + i - 320] = 0;  // zero pad for unclamped tail loads
  }
}

// ---------------- scatter + inline pprefix scan + finalize offsets ----------------
__global__ __launch_bounds__(256) void scatter_kernel(
    const int* __restrict__ src, const int* __restrict__ dst,
    const int* __restrict__ offsets, const int* __restrict__ partials,
    int* __restrict__ cursor, int* __restrict__ csr_src,
    int* __restrict__ offs2, int E, int N, int nb) {
  __shared__ int pp[256];
  __shared__ int ws[4];
  __shared__ int tot;
  const int tid = threadIdx.x, lane = tid & 63, wv = tid >> 6;
  // block-local scan of the (nb<=256) chunk partials
  int v = (tid < nb) ? partials[tid] : 0;
  int incl = wave_incl_scan(v, lane);
  if (lane == 63) ws[wv] = incl;
  __syncthreads();
  int wbase = 0;
  for (int k = 0; k < wv; ++k) wbase += ws[k];
  pp[tid] = wbase + incl - v;
  if (tid == 255) tot = wbase + incl;
  __syncthreads();

  int idx = blockIdx.x * 256 + tid;
  if (idx < E) {
    int d = dst[idx];
    int p = atomicAdd(&cursor[d], 1);
    csr_src[offsets[d] + pp[d >> 8] + p] = src[idx];
  }
  if (idx <= N) {
    offs2[idx] = (idx < N) ? offsets[idx] + pp[idx >> 8] : tot;
  }
}

// ---------------- MFMA bf16 GEMM + fused alpha epilogue ----------------
// SWZ=1: 1D grid, XCD-sibling swizzle (4 col-blocks of a row-tile -> ids
// spaced 8 apart => same XCD back-to-back => A tile L2 reuse).
template <int WM, bool CASTA, int SWZ>
__global__ __launch_bounds__(WM * 64) void mfma_gemm_fused(
    const void* __restrict__ Ain, const ushort_t* __restrict__ Bt,
    ushort_t* __restrict__ C, const float* __restrict__ avs, const float* __restrict__ avd,
    float* __restrict__ as_out, float* __restrict__ ad_out, int M, int Nt, int K, int H) {
  constexpr int BM = WM * 32;
  constexpr int NB = 4 / WM;
  __shared__ ushort_t As[BM * 32];
  __shared__ ushort_t Bs[64 * 32];
  const int t = threadIdx.x;
  const int w = t >> 6, l = t & 63;
  int m0, n0;
  if (SWZ) {
    const int Mtile = (M + BM - 1) / BM;
    const int full = (Mtile & ~7) * 4;
    int id = blockIdx.x, r, c;
    if (id < full) {
      int grp = id >> 5, wd = id & 31;
      r = grp * 8 + (wd & 7);
      c = wd >> 3;
    } else {
      int tl = id - full;
      r = (Mtile & ~7) + (tl >> 2);
      c = tl & 3;
    }
    m0 = r * BM;
    n0 = c * 64;
  } else {
    m0 = blockIdx.y * BM;
    n0 = blockIdx.x * 64;
  }
  const int head = n0 >> 6;

  f32x4 zero4 = {0.f, 0.f, 0.f, 0.f};
  f32x4 acc[2][4];
#pragma unroll
  for (int i = 0; i < 2; ++i)
#pragma unroll
    for (int j = 0; j < 4; ++j) acc[i][j] = zero4;

  const int scol = (l & 3) * 8;
  const ushort_t* Bgb[NB];
  ushort_t* Bsl[NB];
#pragma unroll
  for (int b = 0; b < NB; ++b) {
    int r = (b * WM + w) * 16 + (l >> 2);
    Bgb[b] = Bt + (size_t)(n0 + r) * K + scol;
    Bsl[b] = &Bs[(b * WM + w) * 512];
  }
  const ushort_t* Aga[2];
  ushort_t* Asl[2];
  const float* Axg = nullptr;
  ushort_t* AsWc = nullptr;
  if (CASTA) {
    int ar = t >> 1, ac = (t & 1) * 16;
    Axg = (const float*)Ain + (size_t)min(m0 + ar, M - 1) * K + ac;
    AsWc = &As[ar * 32 + ac];
  } else {
#pragma unroll
    for (int a = 0; a < 2; ++a) {
      int r = (a * WM + w) * 16 + (l >> 2);
      int gr = min(m0 + r, M - 1);
      Aga[a] = (const ushort_t*)Ain + (size_t)gr * K + scol;
      Asl[a] = &As[(a * WM + w) * 512];
    }
  }

  for (int k0 = 0; k0 < K; k0 += 32) {
    if (CASTA) {
      float4 f0 = *(const float4*)(Axg + k0);
      float4 f1 = *(const float4*)(Axg + k0 + 4);
      float4 f2 = *(const float4*)(Axg + k0 + 8);
      float4 f3 = *(const float4*)(Axg + k0 + 12);
      __syncthreads();
#pragma unroll
      for (int b = 0; b < NB; ++b) gld_lds16(Bgb[b] + k0, Bsl[b]);
      ushort8 u0, u1;
      u0[0] = f2bf(f0.x); u0[1] = f2bf(f0.y); u0[2] = f2bf(f0.z); u0[3] = f2bf(f0.w);
      u0[4] = f2bf(f1.x); u0[5] = f2bf(f1.y); u0[6] = f2bf(f1.z); u0[7] = f2bf(f1.w);
      u1[0] = f2bf(f2.x); u1[1] = f2bf(f2.y); u1[2] = f2bf(f2.z); u1[3] = f2bf(f2.w);
      u1[4] = f2bf(f3.x); u1[5] = f2bf(f3.y); u1[6] = f2bf(f3.z); u1[7] = f2bf(f3.w);
      *(ushort8*)AsWc = u0;
      *(ushort8*)(AsWc + 8) = u1;
      __syncthreads();
    } else {
      __syncthreads();
#pragma unroll
      for (int a = 0; a < 2; ++a) gld_lds16(Aga[a] + k0, Asl[a]);
#pragma unroll
      for (int b = 0; b < NB; ++b) gld_lds16(Bgb[b] + k0, Bsl[b]);
      __syncthreads();
    }
    const int kq = (l >> 4) * 8;
    short8 af[2], bfr[4];
#pragma unroll
    for (int i = 0; i < 2; ++i)
      af[i] = *(const short8*)&As[(w * 32 + i * 16 + (l & 15)) * 32 + kq];
#pragma unroll
    for (int j = 0; j < 4; ++j)
      bfr[j] = *(const short8*)&Bs[(j * 16 + (l & 15)) * 32 + kq];
#pragma unroll
    for (int i = 0; i < 2; ++i)
#pragma unroll
      for (int j = 0; j < 4; ++j)
        acc[i][j] = __builtin_amdgcn_mfma_f32_16x16x32_bf16(af[i], bfr[j], acc[i][j], 0, 0, 0);
  }

  const int rbase = m0 + w * 32 + (l >> 4) * 4;
  const int cbase = n0 + (l & 15);
#pragma unroll
  for (int i = 0; i < 2; ++i)
#pragma unroll
    for (int j = 0; j < 4; ++j)
#pragma unroll
      for (int r = 0; r < 4; ++r) {
        int row = rbase + i * 16 + r;
        if (row < M) C[(size_t)row * Nt + cbase + j * 16] = f2bf(acc[i][j][r]);
      }

  float asw[4], adw[4];
#pragma unroll
  for (int j = 0; j < 4; ++j) {
    asw[j] = avs[head * 64 + (l & 15) + j * 16];
    adw[j] = avd[head * 64 + (l & 15) + j * 16];
  }
#pragma unroll
  for (int i = 0; i < 2; ++i)
#pragma unroll
    for (int r = 0; r < 4; ++r) {
      float s_ = acc[i][0][r] * asw[0] + acc[i][1][r] * asw[1] +
                 acc[i][2][r] * asw[2] + acc[i][3][r] * asw[3];
      float d_ = acc[i][0][r] * adw[0] + acc[i][1][r] * adw[1] +
                 acc[i][2][r] * adw[2] + acc[i][3][r] * adw[3];
#pragma unroll
      for (int o = 1; o < 16; o <<= 1) {
        s_ += __shfl_xor(s_, o, 64);
        d_ += __shfl_xor(d_, o, 64);
      }
      if ((l & 15) == 0) {
        int row = rbase + i * 16 + r;
        if (row < M) {
          as_out[(size_t)row * H + head] = s_;
          ad_out[(size_t)row * H + head] = d_;
        }
      }
    }
}

// ---------------- layer 1 agg: inline weights via wave-local LDS ----------------
__global__ __launch_bounds__(256) void agg1_kernel(
    const ushort_t* __restrict__ h1, const int* __restrict__ offsets,
    const int* __restrict__ csr, const float* __restrict__ as1,
    const float* __restrict__ ad1,
    const float* __restrict__ S1, const float* __restrict__ T1,
    ushort_t* __restrict__ out, int N) {
  __shared__ float ldsW[4][64][4];
  __shared__ int ldsS[4][64];
  const int wv = threadIdx.x >> 6;
  int n = blockIdx.x * 4 + wv;
  int l = threadIdx.x & 63;
  if (n >= N) return;
  const int g = l >> 5, ll = l & 31, hh = ll >> 3;
  int off = offsets[n], deg = offsets[n + 1] - off;
  const int* csrp = csr + off;
  const size_t hoff = (size_t)ll * 8;
  float4 adn = *(const float4*)&ad1[n * 4];

  float acc[8] = {0, 0, 0, 0, 0, 0, 0, 0};
  float ds[4] = {0, 0, 0, 0};

  for (int base = 0; base < deg; base += 64) {
    int cnt = min(64, deg - base);
    int s = 0;
    float4 w4 = make_float4(0.f, 0.f, 0.f, 0.f);
    if (l < cnt) {
      s = csrp[base + l];  // coalesced
      float4 a4 = *(const float4*)&as1[s * 4];
      w4.x = __expf(leaky02(a4.x + adn.x));
      w4.y = __expf(leaky02(a4.y + adn.y));
      w4.z = __expf(leaky02(a4.z + adn.z));
      w4.w = __expf(leaky02(a4.w + adn.w));
    }
    ldsS[wv][l] = s;
    *(float4*)&ldsW[wv][l][0] = w4;
    ds[0] += w4.x; ds[1] += w4.y; ds[2] += w4.z; ds[3] += w4.w;
    for (int j = 0; j < cnt; j += 8) {
      int e0 = j + g, e1 = j + 2 + g, e2 = j + 4 + g, e3 = j + 6 + g;  // all <= 63
      int s0 = ldsS[wv][e0], s1 = ldsS[wv][e1], s2 = ldsS[wv][e2], s3 = ldsS[wv][e3];
      float w0 = ldsW[wv][e0][hh], w1 = ldsW[wv][e1][hh];
      float w2 = ldsW[wv][e2][hh], w3 = ldsW[wv][e3][hh];
      ushort8 r0 = *(const ushort8*)&h1[(size_t)s0 * 256 + hoff];
      ushort8 r1 = *(const ushort8*)&h1[(size_t)s1 * 256 + hoff];
      ushort8 r2 = *(const ushort8*)&h1[(size_t)s2 * 256 + hoff];
      ushort8 r3 = *(const ushort8*)&h1[(size_t)s3 * 256 + hoff];
#pragma unroll
      for (int k = 0; k < 8; ++k) acc[k] = fmaf(w0, bf2f(r0[k]), acc[k]);
#pragma unroll
      for (int k = 0; k < 8; ++k) acc[k] = fmaf(w1, bf2f(r1[k]), acc[k]);
#pragma unroll
      for (int k = 0; k < 8; ++k) acc[k] = fmaf(w2, bf2f(r2[k]), acc[k]);
#pragma unroll
      for (int k = 0; k < 8; ++k) acc[k] = fmaf(w3, bf2f(r3[k]), acc[k]);
    }
  }
#pragma unroll
  for (int k = 0; k < 8; ++k) acc[k] += __shfl_xor(acc[k], 32, 64);
  float den[4];
#pragma unroll
  for (int h = 0; h < 4; ++h) den[h] = wave_sum(ds[h]);

  float4 asn = *(const float4*)&as1[n * 4];
  float wsf[4];
  wsf[0] = __expf(leaky02(asn.x + adn.x));
  wsf[1] = __expf(leaky02(asn.y + adn.y));
  wsf[2] = __expf(leaky02(asn.z + adn.z));
  wsf[3] = __expf(leaky02(asn.w + adn.w));
  ushort8 hn = *(const ushort8*)&h1[(size_t)n * 256 + hoff];
  float wsh = wsf[hh];
#pragma unroll
  for (int k = 0; k < 8; ++k) acc[k] = fmaf(wsh, bf2f(hn[k]), acc[k]);
  float inv = 1.f / (den[hh] + wsh + 1e-16f);

  int c0 = ll * 8 + g * 4;
  float4 Sv = *(const float4*)&S1[c0];
  float4 Tv = *(const float4*)&T1[c0];
  float Sf[4] = {Sv.x, Sv.y, Sv.z, Sv.w};
  float Tf[4] = {Tv.x, Tv.y, Tv.z, Tv.w};
  ushort4v o4;
#pragma unroll
  for (int q = 0; q < 4; ++q) {
    float o = fmaf(acc[g * 4 + q], inv * Sf[q], Tf[q]);
    o4[q] = f2bf(elu_fast(o));
  }
  *(ushort4v*)&out[(size_t)n * 256 + c0] = o4;
}

// ---------------- layer 2 agg: inline weights, 16 edges/iter, fused heads ----------------
__global__ __launch_bounds__(256) void agg2_kernel(
    const ushort_t* __restrict__ h2, const int* __restrict__ offsets,
    const int* __restrict__ csr, const float* __restrict__ as2,
    const float* __restrict__ ad2,
    const float* __restrict__ S2, const float* __restrict__ T2,
    const float* __restrict__ Wr, const float* __restrict__ br,
    const float* __restrict__ Wc, const float* __restrict__ bc,
    float* __restrict__ out_reg, float* __restrict__ out_clf, int N) {
  __shared__ float ldsW[4][64];
  __shared__ int ldsS[4][64];
  const int wv = threadIdx.x >> 6;
  int n = blockIdx.x * 4 + wv;
  int l = threadIdx.x & 63;
  if (n >= N) return;
  const int g = l >> 4, ll = l & 15;
  int off = offsets[n], deg = offsets[n + 1] - off;
  const int* csrp = csr + off;
  const size_t hoff = (size_t)ll * 4;
  float adn = ad2[n];

  float acc[4] = {0, 0, 0, 0};
  float ds = 0.f;

  for (int base = 0; base < deg; base += 64) {
    int cnt = min(64, deg - base);
    int s = 0;
    float wv_ = 0.f;
    if (l < cnt) {
      s = csrp[base + l];
      wv_ = __expf(leaky02(as2[s] + adn));
    }
    ldsS[wv][l] = s;
    ldsW[wv][l] = wv_;
    ds += wv_;
    for (int j = 0; j < cnt; j += 16) {
      int e0 = j + g, e1 = j + 4 + g, e2 = j + 8 + g, e3 = j + 12 + g;  // <= 63
      int s0 = ldsS[wv][e0], s1 = ldsS[wv][e1], s2 = ldsS[wv][e2], s3 = ldsS[wv][e3];
      float w0 = ldsW[wv][e0], w1 = ldsW[wv][e1], w2 = ldsW[wv][e2], w3 = ldsW[wv][e3];
      ushort4v r0 = *(const ushort4v*)&h2[(size_t)s0 * 64 + hoff];
      ushort4v r1 = *(const ushort4v*)&h2[(size_t)s1 * 64 + hoff];
      ushort4v r2 = *(const ushort4v*)&h2[(size_t)s2 * 64 + hoff];
      ushort4v r3 = *(const ushort4v*)&h2[(size_t)s3 * 64 + hoff];
#pragma unroll
      for (int k = 0; k < 4; ++k) acc[k] = fmaf(w0, bf2f(r0[k]), acc[k]);
#pragma unroll
      for (int k = 0; k < 4; ++k) acc[k] = fmaf(w1, bf2f(r1[k]), acc[k]);
#pragma unroll
      for (int k = 0; k < 4; ++k) acc[k] = fmaf(w2, bf2f(r2[k]), acc[k]);
#pragma unroll
      for (int k = 0; k < 4; ++k) acc[k] = fmaf(w3, bf2f(r3[k]), acc[k]);
    }
  }
#pragma unroll
  for (int k = 0; k < 4; ++k) {
    acc[k] += __shfl_xor(acc[k], 16, 64);
    acc[k] += __shfl_xor(acc[k], 32, 64);
  }
  float den = wave_sum(ds);
  float ws = __expf(leaky02(as2[n] + adn));
  ushort4v hn = *(const ushort4v*)&h2[(size_t)n * 64 + hoff];
#pragma unroll
  for (int k = 0; k < 4; ++k) acc[k] = fmaf(ws, bf2f(hn[k]), acc[k]);
  float inv = 1.f / (den + ws + 1e-16f);

  int c0 = ll * 4;
  float4 Sv = *(const float4*)&S2[c0];
  float4 Tv = *(const float4*)&T2[c0];
  float4 wr = *(const float4*)&Wr[c0];
  float4 wc = *(const float4*)&Wc[c0];
  float Sf[4] = {Sv.x, Sv.y, Sv.z, Sv.w};
  float Tf[4] = {Tv.x, Tv.y, Tv.z, Tv.w};
  float wrf[4] = {wr.x, wr.y, wr.z, wr.w};
  float wcf[4] = {wc.x, wc.y, wc.z, wc.w};
  float rs = 0.f, cs = 0.f;
#pragma unroll
  for (int q = 0; q < 4; ++q) {
    float o = fmaf(acc[q], inv * Sf[q], Tf[q]);
    o = elu_fast(o);
    rs = fmaf(o, wrf[q], rs);
    cs = fmaf(o, wcf[q], cs);
  }
#pragma unroll
  for (int o = 1; o < 16; o <<= 1) {
    rs += __shfl_xor(rs, o, 64);
    cs += __shfl_xor(cs, o, 64);
  }
  if (l == 0) {
    out_reg[n] = rs + br[0];
    float z = cs + bc[0];
    out_clf[n] = 1.f / (1.f + __expf(-z));
  }
}

// ---------------- launcher ----------------
extern "C" void kernel_launch(void* const* d_in, const int* in_sizes, int n_in,
                              void* d_out, int out_size, void* d_ws, size_t ws_size,
                              hipStream_t stream) {
  const float* x      = (const float*)d_in[0];
  const int*   ei     = (const int*)d_in[1];
  const float* W1     = (const float*)d_in[2];
  const float* a_src1 = (const float*)d_in[3];
  const float* a_dst1 = (const float*)d_in[4];
  const float* b1     = (const float*)d_in[5];
  const float* bn1w   = (const float*)d_in[6];
  const float* bn1b   = (const float*)d_in[7];
  const float* bn1m   = (const float*)d_in[8];
  const float* bn1v   = (const float*)d_in[9];
  const float* W2     = (const float*)d_in[10];
  const float* a_src2 = (const float*)d_in[11];
  const float* a_dst2 = (const float*)d_in[12];
  const float* b2     = (const float*)d_in[13];
  const float* bn2w   = (const float*)d_in[14];
  const float* bn2b   = (const float*)d_in[15];
  const float* bn2m   = (const float*)d_in[16];
  const float* bn2v   = (const float*)d_in[17];
  const float* Wr     = (const float*)d_in[18];
  const float* br     = (const float*)d_in[19];
  const float* Wc     = (const float*)d_in[20];
  const float* bc     = (const float*)d_in[21];

  const int N = in_sizes[0] / 256;  // 50000
  const int E = in_sizes[1] / 2;    // 400000
  const int* srcv = ei;
  const int* dstv = ei + E;

  char* w = (char*)d_ws;
  auto alloc = [&](size_t bytes) {
    char* p = w;
    w += (bytes + 255) & ~(size_t)255;
    return p;
  };
  const int nb = (N + 255) / 256;  // 196 chunks of 256
  const size_t nbytes_rounded = ((size_t)N * 4 + 255) & ~(size_t)255;
  int* counts    = (int*)alloc((size_t)N * 4);
  int* cursor    = (int*)alloc((size_t)N * 4);  // contiguous with counts
  int* offsets   = (int*)alloc((size_t)N * 4);  // chunk-local scan
  int* offs2     = (int*)alloc((size_t)(N + 1) * 4);  // finalized
  int* partials  = (int*)alloc((size_t)nb * 4);
  int* csr_src   = (int*)alloc((size_t)(E + 64) * 4);  // +64 zero pad
  float* as1     = (float*)alloc((size_t)N * 4 * 4);
  float* ad1     = (float*)alloc((size_t)N * 4 * 4);
  float* as2     = (float*)alloc((size_t)N * 4);
  float* ad2     = (float*)alloc((size_t)N * 4);
  float* S1      = (float*)alloc(256 * 4);
  float* T1      = (float*)alloc(256 * 4);
  float* S2      = (float*)alloc(64 * 4);
  float* T2      = (float*)alloc(64 * 4);
  ushort_t* W1t  = (ushort_t*)alloc((size_t)256 * 256 * 2);
  ushort_t* W2t  = (ushort_t*)alloc((size_t)64 * 256 * 2);
  ushort_t* h1b  = (ushort_t*)alloc((size_t)N * 256 * 2);
  ushort_t* h1a  = (ushort_t*)alloc((size_t)N * 256 * 2);
  ushort_t* h2b  = (ushort_t*)alloc((size_t)N * 64 * 2);

  float* out_reg = (float*)d_out;

  // graph build (4 dispatches)
  hipMemsetAsync(counts, 0, nbytes_rounded * 2, stream);  // counts + cursor
  hist_kernel<<<(E + 255) / 256, 256, 0, stream>>>(dstv, counts, E);
  scan_chunks_kernel<<<nb, 256, 0, stream>>>(counts, offsets, partials, N, E, csr_src,
                                             W1, W2, W1t, W2t,
                                             b1, bn1w, bn1b, bn1m, bn1v,
                                             b2, bn2w, bn2b, bn2m, bn2v,
                                             S1, T1, S2, T2);
  {
    int items = max(E, N + 1);
    scatter_kernel<<<(items + 255) / 256, 256, 0, stream>>>(srcv, dstv, offsets, partials,
                                                            cursor, csr_src, offs2, E, N, nb);
  }

  const int nwb = (N + 3) / 4;

  // layer 1 (gemm1: 1D grid, XCD-sibling swizzle)
  const int mtiles = (N + 127) / 128;
  mfma_gemm_fused<4, true, 1><<<mtiles * 4, 256, 0, stream>>>(
      x, W1t, h1b, a_src1, a_dst1, as1, ad1, N, 256, 256, 4);
  agg1_kernel<<<nwb, 256, 0, stream>>>(h1b, offs2, csr_src, as1, ad1, S1, T1, h1a, N);

  // layer 2
  dim3 g2(1, (N + 63) / 64);
  mfma_gemm_fused<2, false, 0><<<g2, 128, 0, stream>>>(h1a, W2t, h2b, a_src2, a_dst2,
                                                       as2, ad2, N, 64, 256, 1);
  agg2_kernel<<<nwb, 256, 0, stream>>>(h2b, offs2, csr_src, as2, ad2, S2, T2,
                                       Wr, br, Wc, bc, out_reg, out_reg + N, N);
}

// Round 10
// 265.748 us; speedup vs baseline: 4.9912x; 1.0216x over previous
//
#include <hip/hip_runtime.h>
#include <math.h>

// MultiTaskGNN: 2-layer GAT + BN + ELU + two heads. N=50000, E=400000.
// R10: h1 stored as fp8-e4m3 for the agg1 gather (halves the L3-bound gather
// traffic: agg1 FETCH 113MB -> ~60MB). Alphas still from fp32 acc; h1a/h2
// stay bf16. Everything else frozen from R9 (271us).

typedef unsigned short ushort_t;
typedef unsigned char uchar_t;
typedef __attribute__((ext_vector_type(8))) unsigned short ushort8;
typedef __attribute__((ext_vector_type(4))) unsigned short ushort4v;
typedef __attribute__((ext_vector_type(8))) short short8;
typedef __attribute__((ext_vector_type(4))) float f32x4;
typedef __attribute__((ext_vector_type(2))) float f32x2;

#define EPS_BN 1e-5f

__device__ __forceinline__ ushort_t f2bf(float f) {  // RNE
  unsigned u = __float_as_uint(f);
  unsigned r = u + 0x7fffu + ((u >> 16) & 1u);
  return (ushort_t)(r >> 16);
}
__device__ __forceinline__ float bf2f(ushort_t h) {
  return __uint_as_float((unsigned)h << 16);
}
__device__ __forceinline__ uchar_t f2fp8(float f) {  // e4m3 via HW cvt (RNE, sat)
  return (uchar_t)(__builtin_amdgcn_cvt_pk_fp8_f32(f, f, 0, false) & 0xff);
}
__device__ __forceinline__ void fp8x8_to_f32(uint2 q, float* f) {
  f32x2 a = __builtin_amdgcn_cvt_pk_f32_fp8(q.x, false);
  f32x2 b = __builtin_amdgcn_cvt_pk_f32_fp8(q.x, true);
  f32x2 c = __builtin_amdgcn_cvt_pk_f32_fp8(q.y, false);
  f32x2 d = __builtin_amdgcn_cvt_pk_f32_fp8(q.y, true);
  f[0] = a.x; f[1] = a.y; f[2] = b.x; f[3] = b.y;
  f[4] = c.x; f[5] = c.y; f[6] = d.x; f[7] = d.y;
}
__device__ __forceinline__ float leaky02(float x) { return x >= 0.f ? x : 0.2f * x; }
__device__ __forceinline__ float elu_fast(float x) {
  return x > 0.f ? x : __expf(x) - 1.f;
}
__device__ __forceinline__ float wave_sum(float v) {
#pragma unroll
  for (int o = 1; o < 64; o <<= 1) v += __shfl_xor(v, o, 64);
  return v;
}
__device__ __forceinline__ int wave_incl_scan(int v, int lane) {
#pragma unroll
  for (int off = 1; off < 64; off <<= 1) {
    int t = __shfl_up(v, off, 64);
    if (lane >= off) v += t;
  }
  return v;
}

__device__ __forceinline__ void gld_lds16(const ushort_t* g, ushort_t* l) {
  __builtin_amdgcn_global_load_lds(
      (const __attribute__((address_space(1))) unsigned int*)g,
      (__attribute__((address_space(3))) unsigned int*)l, 16, 0, 0);
}

// ---------------- hist ----------------
__global__ void hist_kernel(const int* __restrict__ dst, int* __restrict__ counts, int E) {
  int e = blockIdx.x * blockDim.x + threadIdx.x;
  if (e < E) atomicAdd(&counts[dst[e]], 1);
}

// ---------------- scan chunks (256/block) + merged prep work ----------------
__global__ __launch_bounds__(256) void scan_chunks_kernel(
    const int* __restrict__ counts, int* __restrict__ offsets, int* __restrict__ partials,
    int N, int E, int* __restrict__ csr_src,
    const float* __restrict__ W1, const float* __restrict__ W2,
    ushort_t* __restrict__ W1t, ushort_t* __restrict__ W2t,
    const float* __restrict__ b1, const float* __restrict__ bn1w,
    const float* __restrict__ bn1b, const float* __restrict__ bn1m,
    const float* __restrict__ bn1v,
    const float* __restrict__ b2, const float* __restrict__ bn2w,
    const float* __restrict__ bn2b, const float* __restrict__ bn2m,
    const float* __restrict__ bn2v,
    float* __restrict__ S1, float* __restrict__ T1,
    float* __restrict__ S2, float* __restrict__ T2) {
  __shared__ int ws[4];
  const int tid = threadIdx.x, lane = tid & 63, wv = tid >> 6;
  const int i = blockIdx.x * 256 + tid;
  const int gsz = gridDim.x * 256;
  int v = (i < N) ? counts[i] : 0;
  int incl = wave_incl_scan(v, lane);
  if (lane == 63) ws[wv] = incl;
  __syncthreads();
  int wbase = 0;
  for (int k = 0; k < wv; ++k) wbase += ws[k];
  if (i < N) offsets[i] = wbase + incl - v;  // chunk-local exclusive
  if (tid == 255) partials[blockIdx.x] = wbase + incl;

  for (int j = i; j < 256 * 256; j += gsz) {
    int k = j >> 8, n2 = j & 255;
    W1t[n2 * 256 + k] = f2bf(W1[j]);
  }
  for (int j = i; j < 256 * 64; j += gsz) {
    int k = j >> 6, n2 = j & 63;
    W2t[n2 * 256 + k] = f2bf(W2[j]);
  }
  if (i < 256) {
    float s = bn1w[i] * rsqrtf(bn1v[i] + EPS_BN);
    S1[i] = s;
    T1[i] = (b1[i] - bn1m[i]) * s + bn1b[i];
  } else if (i < 320) {
    int j = i - 256;
    float s = bn2w[j] * rsqrtf(bn2v[j] + EPS_BN);
    S2[j] = s;
    T2[j] = (b2[j] - bn2m[j]) * s + bn2b[j];
  } else if (i < 384) {
    csr_src[E + i - 320] = 0;  // zero pad for unclamped tail loads
  }
}

// ---------------- scatter + inline pprefix scan + finalize offsets ----------------
__global__ __launch_bounds__(256) void scatter_kernel(
    const int* __restrict__ src, const int* __restrict__ dst,
    const int* __restrict__ offsets, const int* __restrict__ partials,
    int* __restrict__ cursor, int* __restrict__ csr_src,
    int* __restrict__ offs2, int E, int N, int nb) {
  __shared__ int pp[256];
  __shared__ int ws[4];
  __shared__ int tot;
  const int tid = threadIdx.x, lane = tid & 63, wv = tid >> 6;
  int v = (tid < nb) ? partials[tid] : 0;
  int incl = wave_incl_scan(v, lane);
  if (lane == 63) ws[wv] = incl;
  __syncthreads();
  int wbase = 0;
  for (int k = 0; k < wv; ++k) wbase += ws[k];
  pp[tid] = wbase + incl - v;
  if (tid == 255) tot = wbase + incl;
  __syncthreads();

  int idx = blockIdx.x * 256 + tid;
  if (idx < E) {
    int d = dst[idx];
    int p = atomicAdd(&cursor[d], 1);
    csr_src[offsets[d] + pp[d >> 8] + p] = src[idx];
  }
  if (idx <= N) {
    offs2[idx] = (idx < N) ? offsets[idx] + pp[idx >> 8] : tot;
  }
}

// ---------------- MFMA bf16 GEMM + fused alpha epilogue ----------------
// SWZ: XCD-sibling swizzle. OUT8: store C as fp8-e4m3 bytes (else bf16).
template <int WM, bool CASTA, int SWZ, int OUT8>
__global__ __launch_bounds__(WM * 64) void mfma_gemm_fused(
    const void* __restrict__ Ain, const ushort_t* __restrict__ Bt,
    void* __restrict__ Cout, const float* __restrict__ avs, const float* __restrict__ avd,
    float* __restrict__ as_out, float* __restrict__ ad_out, int M, int Nt, int K, int H) {
  constexpr int BM = WM * 32;
  constexpr int NB = 4 / WM;
  __shared__ ushort_t As[BM * 32];
  __shared__ ushort_t Bs[64 * 32];
  const int t = threadIdx.x;
  const int w = t >> 6, l = t & 63;
  int m0, n0;
  if (SWZ) {
    const int Mtile = (M + BM - 1) / BM;
    const int full = (Mtile & ~7) * 4;
    int id = blockIdx.x, r, c;
    if (id < full) {
      int grp = id >> 5, wd = id & 31;
      r = grp * 8 + (wd & 7);
      c = wd >> 3;
    } else {
      int tl = id - full;
      r = (Mtile & ~7) + (tl >> 2);
      c = tl & 3;
    }
    m0 = r * BM;
    n0 = c * 64;
  } else {
    m0 = blockIdx.y * BM;
    n0 = blockIdx.x * 64;
  }
  const int head = n0 >> 6;

  f32x4 zero4 = {0.f, 0.f, 0.f, 0.f};
  f32x4 acc[2][4];
#pragma unroll
  for (int i = 0; i < 2; ++i)
#pragma unroll
    for (int j = 0; j < 4; ++j) acc[i][j] = zero4;

  const int scol = (l & 3) * 8;
  const ushort_t* Bgb[NB];
  ushort_t* Bsl[NB];
#pragma unroll
  for (int b = 0; b < NB; ++b) {
    int r = (b * WM + w) * 16 + (l >> 2);
    Bgb[b] = Bt + (size_t)(n0 + r) * K + scol;
    Bsl[b] = &Bs[(b * WM + w) * 512];
  }
  const ushort_t* Aga[2];
  ushort_t* Asl[2];
  const float* Axg = nullptr;
  ushort_t* AsWc = nullptr;
  if (CASTA) {
    int ar = t >> 1, ac = (t & 1) * 16;
    Axg = (const float*)Ain + (size_t)min(m0 + ar, M - 1) * K + ac;
    AsWc = &As[ar * 32 + ac];
  } else {
#pragma unroll
    for (int a = 0; a < 2; ++a) {
      int r = (a * WM + w) * 16 + (l >> 2);
      int gr = min(m0 + r, M - 1);
      Aga[a] = (const ushort_t*)Ain + (size_t)gr * K + scol;
      Asl[a] = &As[(a * WM + w) * 512];
    }
  }

  for (int k0 = 0; k0 < K; k0 += 32) {
    if (CASTA) {
      float4 f0 = *(const float4*)(Axg + k0);
      float4 f1 = *(const float4*)(Axg + k0 + 4);
      float4 f2 = *(const float4*)(Axg + k0 + 8);
      float4 f3 = *(const float4*)(Axg + k0 + 12);
      __syncthreads();
#pragma unroll
      for (int b = 0; b < NB; ++b) gld_lds16(Bgb[b] + k0, Bsl[b]);
      ushort8 u0, u1;
      u0[0] = f2bf(f0.x); u0[1] = f2bf(f0.y); u0[2] = f2bf(f0.z); u0[3] = f2bf(f0.w);
      u0[4] = f2bf(f1.x); u0[5] = f2bf(f1.y); u0[6] = f2bf(f1.z); u0[7] = f2bf(f1.w);
      u1[0] = f2bf(f2.x); u1[1] = f2bf(f2.y); u1[2] = f2bf(f2.z); u1[3] = f2bf(f2.w);
      u1[4] = f2bf(f3.x); u1[5] = f2bf(f3.y); u1[6] = f2bf(f3.z); u1[7] = f2bf(f3.w);
      *(ushort8*)AsWc = u0;
      *(ushort8*)(AsWc + 8) = u1;
      __syncthreads();
    } else {
      __syncthreads();
#pragma unroll
      for (int a = 0; a < 2; ++a) gld_lds16(Aga[a] + k0, Asl[a]);
#pragma unroll
      for (int b = 0; b < NB; ++b) gld_lds16(Bgb[b] + k0, Bsl[b]);
      __syncthreads();
    }
    const int kq = (l >> 4) * 8;
    short8 af[2], bfr[4];
#pragma unroll
    for (int i = 0; i < 2; ++i)
      af[i] = *(const short8*)&As[(w * 32 + i * 16 + (l & 15)) * 32 + kq];
#pragma unroll
    for (int j = 0; j < 4; ++j)
      bfr[j] = *(const short8*)&Bs[(j * 16 + (l & 15)) * 32 + kq];
#pragma unroll
    for (int i = 0; i < 2; ++i)
#pragma unroll
      for (int j = 0; j < 4; ++j)
        acc[i][j] = __builtin_amdgcn_mfma_f32_16x16x32_bf16(af[i], bfr[j], acc[i][j], 0, 0, 0);
  }

  const int rbase = m0 + w * 32 + (l >> 4) * 4;
  const int cbase = n0 + (l & 15);
#pragma unroll
  for (int i = 0; i < 2; ++i)
#pragma unroll
    for (int j = 0; j < 4; ++j)
#pragma unroll
      for (int r = 0; r < 4; ++r) {
        int row = rbase + i * 16 + r;
        if (row < M) {
          if (OUT8)
            ((uchar_t*)Cout)[(size_t)row * Nt + cbase + j * 16] = f2fp8(acc[i][j][r]);
          else
            ((ushort_t*)Cout)[(size_t)row * Nt + cbase + j * 16] = f2bf(acc[i][j][r]);
        }
      }

  float asw[4], adw[4];
#pragma unroll
  for (int j = 0; j < 4; ++j) {
    asw[j] = avs[head * 64 + (l & 15) + j * 16];
    adw[j] = avd[head * 64 + (l & 15) + j * 16];
  }
#pragma unroll
  for (int i = 0; i < 2; ++i)
#pragma unroll
    for (int r = 0; r < 4; ++r) {
      float s_ = acc[i][0][r] * asw[0] + acc[i][1][r] * asw[1] +
                 acc[i][2][r] * asw[2] + acc[i][3][r] * asw[3];
      float d_ = acc[i][0][r] * adw[0] + acc[i][1][r] * adw[1] +
                 acc[i][2][r] * adw[2] + acc[i][3][r] * adw[3];
#pragma unroll
      for (int o = 1; o < 16; o <<= 1) {
        s_ += __shfl_xor(s_, o, 64);
        d_ += __shfl_xor(d_, o, 64);
      }
      if ((l & 15) == 0) {
        int row = rbase + i * 16 + r;
        if (row < M) {
          as_out[(size_t)row * H + head] = s_;
          ad_out[(size_t)row * H + head] = d_;
        }
      }
    }
}

// ---------------- layer 1 agg: fp8 h1 gather, inline weights, wave-local LDS ----------------
__global__ __launch_bounds__(256) void agg1_kernel(
    const uchar_t* __restrict__ h1, const int* __restrict__ offsets,
    const int* __restrict__ csr, const float* __restrict__ as1,
    const float* __restrict__ ad1,
    const float* __restrict__ S1, const float* __restrict__ T1,
    ushort_t* __restrict__ out, int N) {
  __shared__ float ldsW[4][64][4];
  __shared__ int ldsS[4][64];
  const int wv = threadIdx.x >> 6;
  int n = blockIdx.x * 4 + wv;
  int l = threadIdx.x & 63;
  if (n >= N) return;
  const int g = l >> 5, ll = l & 31, hh = ll >> 3;
  int off = offsets[n], deg = offsets[n + 1] - off;
  const int* csrp = csr + off;
  const size_t hoff = (size_t)ll * 8;  // 8 fp8 bytes per lane
  float4 adn = *(const float4*)&ad1[n * 4];

  float acc[8] = {0, 0, 0, 0, 0, 0, 0, 0};
  float ds[4] = {0, 0, 0, 0};

  for (int base = 0; base < deg; base += 64) {
    int cnt = min(64, deg - base);
    int s = 0;
    float4 w4 = make_float4(0.f, 0.f, 0.f, 0.f);
    if (l < cnt) {
      s = csrp[base + l];  // coalesced
      float4 a4 = *(const float4*)&as1[s * 4];
      w4.x = __expf(leaky02(a4.x + adn.x));
      w4.y = __expf(leaky02(a4.y + adn.y));
      w4.z = __expf(leaky02(a4.z + adn.z));
      w4.w = __expf(leaky02(a4.w + adn.w));
    }
    ldsS[wv][l] = s;
    *(float4*)&ldsW[wv][l][0] = w4;
    ds[0] += w4.x; ds[1] += w4.y; ds[2] += w4.z; ds[3] += w4.w;
    for (int j = 0; j < cnt; j += 8) {
      int e0 = j + g, e1 = j + 2 + g, e2 = j + 4 + g, e3 = j + 6 + g;  // all <= 63
      int s0 = ldsS[wv][e0], s1 = ldsS[wv][e1], s2 = ldsS[wv][e2], s3 = ldsS[wv][e3];
      float w0 = ldsW[wv][e0][hh], w1 = ldsW[wv][e1][hh];
      float w2 = ldsW[wv][e2][hh], w3 = ldsW[wv][e3][hh];
      uint2 q0 = *(const uint2*)&h1[(size_t)s0 * 256 + hoff];
      uint2 q1 = *(const uint2*)&h1[(size_t)s1 * 256 + hoff];
      uint2 q2 = *(const uint2*)&h1[(size_t)s2 * 256 + hoff];
      uint2 q3 = *(const uint2*)&h1[(size_t)s3 * 256 + hoff];
      float f0[8], f1[8], f2[8], f3[8];
      fp8x8_to_f32(q0, f0);
      fp8x8_to_f32(q1, f1);
      fp8x8_to_f32(q2, f2);
      fp8x8_to_f32(q3, f3);
#pragma unroll
      for (int k = 0; k < 8; ++k) acc[k] = fmaf(w0, f0[k], acc[k]);
#pragma unroll
      for (int k = 0; k < 8; ++k) acc[k] = fmaf(w1, f1[k], acc[k]);
#pragma unroll
      for (int k = 0; k < 8; ++k) acc[k] = fmaf(w2, f2[k], acc[k]);
#pragma unroll
      for (int k = 0; k < 8; ++k) acc[k] = fmaf(w3, f3[k], acc[k]);
    }
  }
#pragma unroll
  for (int k = 0; k < 8; ++k) acc[k] += __shfl_xor(acc[k], 32, 64);
  float den[4];
#pragma unroll
  for (int h = 0; h < 4; ++h) den[h] = wave_sum(ds[h]);

  float4 asn = *(const float4*)&as1[n * 4];
  float wsf[4];
  wsf[0] = __expf(leaky02(asn.x + adn.x));
  wsf[1] = __expf(leaky02(asn.y + adn.y));
  wsf[2] = __expf(leaky02(asn.z + adn.z));
  wsf[3] = __expf(leaky02(asn.w + adn.w));
  uint2 qn = *(const uint2*)&h1[(size_t)n * 256 + hoff];
  float fn[8];
  fp8x8_to_f32(qn, fn);
  float wsh = wsf[hh];
#pragma unroll
  for (int k = 0; k < 8; ++k) acc[k] = fmaf(wsh, fn[k], acc[k]);
  float inv = 1.f / (den[hh] + wsh + 1e-16f);

  int c0 = ll * 8 + g * 4;
  float4 Sv = *(const float4*)&S1[c0];
  float4 Tv = *(const float4*)&T1[c0];
  float Sf[4] = {Sv.x, Sv.y, Sv.z, Sv.w};
  float Tf[4] = {Tv.x, Tv.y, Tv.z, Tv.w};
  ushort4v o4;
#pragma unroll
  for (int q = 0; q < 4; ++q) {
    float o = fmaf(acc[g * 4 + q], inv * Sf[q], Tf[q]);
    o4[q] = f2bf(elu_fast(o));
  }
  *(ushort4v*)&out[(size_t)n * 256 + c0] = o4;
}

// ---------------- layer 2 agg: inline weights, 16 edges/iter, fused heads ----------------
__global__ __launch_bounds__(256) void agg2_kernel(
    const ushort_t* __restrict__ h2, const int* __restrict__ offsets,
    const int* __restrict__ csr, const float* __restrict__ as2,
    const float* __restrict__ ad2,
    const float* __restrict__ S2, const float* __restrict__ T2,
    const float* __restrict__ Wr, const float* __restrict__ br,
    const float* __restrict__ Wc, const float* __restrict__ bc,
    float* __restrict__ out_reg, float* __restrict__ out_clf, int N) {
  __shared__ float ldsW[4][64];
  __shared__ int ldsS[4][64];
  const int wv = threadIdx.x >> 6;
  int n = blockIdx.x * 4 + wv;
  int l = threadIdx.x & 63;
  if (n >= N) return;
  const int g = l >> 4, ll = l & 15;
  int off = offsets[n], deg = offsets[n + 1] - off;
  const int* csrp = csr + off;
  const size_t hoff = (size_t)ll * 4;
  float adn = ad2[n];

  float acc[4] = {0, 0, 0, 0};
  float ds = 0.f;

  for (int base = 0; base < deg; base += 64) {
    int cnt = min(64, deg - base);
    int s = 0;
    float wv_ = 0.f;
    if (l < cnt) {
      s = csrp[base + l];
      wv_ = __expf(leaky02(as2[s] + adn));
    }
    ldsS[wv][l] = s;
    ldsW[wv][l] = wv_;
    ds += wv_;
    for (int j = 0; j < cnt; j += 16) {
      int e0 = j + g, e1 = j + 4 + g, e2 = j + 8 + g, e3 = j + 12 + g;  // <= 63
      int s0 = ldsS[wv][e0], s1 = ldsS[wv][e1], s2 = ldsS[wv][e2], s3 = ldsS[wv][e3];
      float w0 = ldsW[wv][e0], w1 = ldsW[wv][e1], w2 = ldsW[wv][e2], w3 = ldsW[wv][e3];
      ushort4v r0 = *(const ushort4v*)&h2[(size_t)s0 * 64 + hoff];
      ushort4v r1 = *(const ushort4v*)&h2[(size_t)s1 * 64 + hoff];
      ushort4v r2 = *(const ushort4v*)&h2[(size_t)s2 * 64 + hoff];
      ushort4v r3 = *(const ushort4v*)&h2[(size_t)s3 * 64 + hoff];
#pragma unroll
      for (int k = 0; k < 4; ++k) acc[k] = fmaf(w0, bf2f(r0[k]), acc[k]);
#pragma unroll
      for (int k = 0; k < 4; ++k) acc[k] = fmaf(w1, bf2f(r1[k]), acc[k]);
#pragma unroll
      for (int k = 0; k < 4; ++k) acc[k] = fmaf(w2, bf2f(r2[k]), acc[k]);
#pragma unroll
      for (int k = 0; k < 4; ++k) acc[k] = fmaf(w3, bf2f(r3[k]), acc[k]);
    }
  }
#pragma unroll
  for (int k = 0; k < 4; ++k) {
    acc[k] += __shfl_xor(acc[k], 16, 64);
    acc[k] += __shfl_xor(acc[k], 32, 64);
  }
  float den = wave_sum(ds);
  float ws = __expf(leaky02(as2[n] + adn));
  ushort4v hn = *(const ushort4v*)&h2[(size_t)n * 64 + hoff];
#pragma unroll
  for (int k = 0; k < 4; ++k) acc[k] = fmaf(ws, bf2f(hn[k]), acc[k]);
  float inv = 1.f / (den + ws + 1e-16f);

  int c0 = ll * 4;
  float4 Sv = *(const float4*)&S2[c0];
  float4 Tv = *(const float4*)&T2[c0];
  float4 wr = *(const float4*)&Wr[c0];
  float4 wc = *(const float4*)&Wc[c0];
  float Sf[4] = {Sv.x, Sv.y, Sv.z, Sv.w};
  float Tf[4] = {Tv.x, Tv.y, Tv.z, Tv.w};
  float wrf[4] = {wr.x, wr.y, wr.z, wr.w};
  float wcf[4] = {wc.x, wc.y, wc.z, wc.w};
  float rs = 0.f, cs = 0.f;
#pragma unroll
  for (int q = 0; q < 4; ++q) {
    float o = fmaf(acc[q], inv * Sf[q], Tf[q]);
    o = elu_fast(o);
    rs = fmaf(o, wrf[q], rs);
    cs = fmaf(o, wcf[q], cs);
  }
#pragma unroll
  for (int o = 1; o < 16; o <<= 1) {
    rs += __shfl_xor(rs, o, 64);
    cs += __shfl_xor(cs, o, 64);
  }
  if (l == 0) {
    out_reg[n] = rs + br[0];
    float z = cs + bc[0];
    out_clf[n] = 1.f / (1.f + __expf(-z));
  }
}

// ---------------- launcher ----------------
extern "C" void kernel_launch(void* const* d_in, const int* in_sizes, int n_in,
                              void* d_out, int out_size, void* d_ws, size_t ws_size,
                              hipStream_t stream) {
  const float* x      = (const float*)d_in[0];
  const int*   ei     = (const int*)d_in[1];
  const float* W1     = (const float*)d_in[2];
  const float* a_src1 = (const float*)d_in[3];
  const float* a_dst1 = (const float*)d_in[4];
  const float* b1     = (const float*)d_in[5];
  const float* bn1w   = (const float*)d_in[6];
  const float* bn1b   = (const float*)d_in[7];
  const float* bn1m   = (const float*)d_in[8];
  const float* bn1v   = (const float*)d_in[9];
  const float* W2     = (const float*)d_in[10];
  const float* a_src2 = (const float*)d_in[11];
  const float* a_dst2 = (const float*)d_in[12];
  const float* b2     = (const float*)d_in[13];
  const float* bn2w   = (const float*)d_in[14];
  const float* bn2b   = (const float*)d_in[15];
  const float* bn2m   = (const float*)d_in[16];
  const float* bn2v   = (const float*)d_in[17];
  const float* Wr     = (const float*)d_in[18];
  const float* br     = (const float*)d_in[19];
  const float* Wc     = (const float*)d_in[20];
  const float* bc     = (const float*)d_in[21];

  const int N = in_sizes[0] / 256;  // 50000
  const int E = in_sizes[1] / 2;    // 400000
  const int* srcv = ei;
  const int* dstv = ei + E;

  char* w = (char*)d_ws;
  auto alloc = [&](size_t bytes) {
    char* p = w;
    w += (bytes + 255) & ~(size_t)255;
    return p;
  };
  const int nb = (N + 255) / 256;  // 196 chunks of 256
  const size_t nbytes_rounded = ((size_t)N * 4 + 255) & ~(size_t)255;
  int* counts    = (int*)alloc((size_t)N * 4);
  int* cursor    = (int*)alloc((size_t)N * 4);  // contiguous with counts
  int* offsets   = (int*)alloc((size_t)N * 4);  // chunk-local scan
  int* offs2     = (int*)alloc((size_t)(N + 1) * 4);  // finalized
  int* partials  = (int*)alloc((size_t)nb * 4);
  int* csr_src   = (int*)alloc((size_t)(E + 64) * 4);  // +64 zero pad
  float* as1     = (float*)alloc((size_t)N * 4 * 4);
  float* ad1     = (float*)alloc((size_t)N * 4 * 4);
  float* as2     = (float*)alloc((size_t)N * 4);
  float* ad2     = (float*)alloc((size_t)N * 4);
  float* S1      = (float*)alloc(256 * 4);
  float* T1      = (float*)alloc(256 * 4);
  float* S2      = (float*)alloc(64 * 4);
  float* T2      = (float*)alloc(64 * 4);
  ushort_t* W1t  = (ushort_t*)alloc((size_t)256 * 256 * 2);
  ushort_t* W2t  = (ushort_t*)alloc((size_t)64 * 256 * 2);
  uchar_t* h1b   = (uchar_t*)alloc((size_t)N * 256);      // fp8 e4m3
  ushort_t* h1a  = (ushort_t*)alloc((size_t)N * 256 * 2); // bf16
  ushort_t* h2b  = (ushort_t*)alloc((size_t)N * 64 * 2);  // bf16

  float* out_reg = (float*)d_out;

  // graph build (4 dispatches)
  hipMemsetAsync(counts, 0, nbytes_rounded * 2, stream);  // counts + cursor
  hist_kernel<<<(E + 255) / 256, 256, 0, stream>>>(dstv, counts, E);
  scan_chunks_kernel<<<nb, 256, 0, stream>>>(counts, offsets, partials, N, E, csr_src,
                                             W1, W2, W1t, W2t,
                                             b1, bn1w, bn1b, bn1m, bn1v,
                                             b2, bn2w, bn2b, bn2m, bn2v,
                                             S1, T1, S2, T2);
  {
    int items = max(E, N + 1);
    scatter_kernel<<<(items + 255) / 256, 256, 0, stream>>>(srcv, dstv, offsets, partials,
                                                            cursor, csr_src, offs2, E, N, nb);
  }

  const int nwb = (N + 3) / 4;

  // layer 1 (gemm1: swizzled, fp8 out)
  const int mtiles = (N + 127) / 128;
  mfma_gemm_fused<4, true, 1, 1><<<mtiles * 4, 256, 0, stream>>>(
      x, W1t, h1b, a_src1, a_dst1, as1, ad1, N, 256, 256, 4);
  agg1_kernel<<<nwb, 256, 0, stream>>>(h1b, offs2, csr_src, as1, ad1, S1, T1, h1a, N);

  // layer 2
  dim3 g2(1, (N + 63) / 64);
  mfma_gemm_fused<2, false, 0, 0><<<g2, 128, 0, stream>>>(h1a, W2t, h2b, a_src2, a_dst2,
                                                          as2, ad2, N, 64, 256, 1);
  agg2_kernel<<<nwb, 256, 0, stream>>>(h2b, offs2, csr_src, as2, ad2, S2, T2,
                                       Wr, br, Wc, bc, out_reg, out_reg + N, N);
}